// Round 5
// baseline (1220.222 us; speedup 1.0000x reference)
//
#include <hip/hip_runtime.h>

typedef unsigned int uint;
typedef unsigned short ushort;

#define NN 4761            // 69*69
#define SZ_S 9043968       // 1024*69*128
#define NEGV -9000000.0f

// ---------------- K1: S = structure_embed @ W_lin^T + b_lin (all f32)
// Block per batch. Thread i (=tid&127) owns output column i, W row i in registers.
__global__ __launch_bounds__(256) void k1_transform(
    const float* __restrict__ se, const float* __restrict__ Wl,
    const float* __restrict__ bl, float* __restrict__ S) {
  __shared__ float seld[69 * 128];  // 35,328 B
  const int tid = threadIdx.x, b = blockIdx.x;
  const int rr = tid >> 7, i = tid & 127;
  float w[128];
  #pragma unroll
  for (int d0 = 0; d0 < 128; d0 += 4) {
    float4 v = *(const float4*)(Wl + i * 128 + d0);
    w[d0] = v.x; w[d0 + 1] = v.y; w[d0 + 2] = v.z; w[d0 + 3] = v.w;
  }
  for (int idx = tid; idx < 69 * 128; idx += 256) seld[idx] = se[b * 69 * 128 + idx];
  __syncthreads();
  const float bias = bl[i];
  for (int k = 0; k < 35; ++k) {
    int r = 2 * k + rr;
    if (r < 69) {
      float acc = bias;
      #pragma unroll
      for (int d0 = 0; d0 < 128; d0 += 4) {
        float4 sv = *(const float4*)(seld + r * 128 + d0);
        acc = fmaf(sv.x, w[d0], acc);
        acc = fmaf(sv.y, w[d0 + 1], acc);
        acc = fmaf(sv.z, w[d0 + 2], acc);
        acc = fmaf(sv.w, w[d0 + 3], acc);
      }
      S[(b * 69 + r) * 128 + i] = acc;
    }
  }
}

// ---------------- K2: alphas (stores am1 = alpha-1): [0..1023]=sem1, [1024..]=sem2, [2048..]=str
__global__ __launch_bounds__(128) void k2_alpha(
    const float* __restrict__ in1, const float* __restrict__ in2,
    const float* __restrict__ S, const float* __restrict__ mask,
    const int* __restrict__ iidx,
    const float* __restrict__ w1p, const float* __restrict__ b1p,
    const float* __restrict__ w2p, const float* __restrict__ b2p,
    const float* __restrict__ wSp, const float* __restrict__ bSp,
    float* __restrict__ alpha) {
  __shared__ float red[3][2];
  const int b = blockIdx.x, d = threadIdx.x;
  const int last = iidx[b * 69 + 68];
  float a1 = 0, a2 = 0, aS = 0, am = 0;
  const float* p1 = in1 + b * 69 * 128 + d;
  const float* p2 = in2 + b * 69 * 128 + d;
  const float* pS = S + b * 69 * 128 + d;
  const float* pm = mask + b * 69;
  for (int n = 0; n < 69; ++n) {
    float m = pm[n];
    a1 += p1[n * 128] * m;
    a2 += p2[n * 128] * m;
    aS += pS[n * 128] * m;
    am += m;
  }
  float z1 = (a1 / am + p1[last * 128]) * w1p[d];
  float z2 = (a2 / am + p2[last * 128]) * w2p[d];
  float zS = (aS / am + pS[last * 128]) * wSp[d];
  for (int off = 32; off >= 1; off >>= 1) {
    z1 += __shfl_down(z1, off);
    z2 += __shfl_down(z2, off);
    zS += __shfl_down(zS, off);
  }
  if ((d & 63) == 0) { int wv = d >> 6; red[0][wv] = z1; red[1][wv] = z2; red[2][wv] = zS; }
  __syncthreads();
  if (d == 0) {
    float r1 = 1.0f / (1.0f + expf(-(red[0][0] + red[0][1] + b1p[0]))) + 1.0f;
    float r2 = 1.0f / (1.0f + expf(-(red[1][0] + red[1][1] + b2p[0]))) + 1.0f;
    float rS = 1.0f / (1.0f + expf(-(red[2][0] + red[2][1] + bSp[0]))) + 1.0f;
    if (r1 == 1.0f) r1 = 1.0001f;
    if (r2 == 1.0f) r2 = 1.0001f;
    if (rS == 1.0f) rS = 1.0001f;
    alpha[b] = r1 - 1.0f;
    alpha[1024 + b] = r2 - 1.0f;
    alpha[2048 + b] = rS - 1.0f;
  }
}

// ---------------- K3: masked leaky scores, one (h, W4, adj) triple per launch.
// dst[b][i][j] f32, row-major. Upper-tri cells (i<=j): shared symmetric dot, per-side k/mask.
__global__ __launch_bounds__(256) void k3_scores(
    const float* __restrict__ h, const float* __restrict__ W4,
    const int* __restrict__ adj, float* __restrict__ dst) {
  const int b = blockIdx.x, tid = threadIdx.x;
  __shared__ float hld[69 * 132];       // 36,432 B (pad 132: bank spread, 16B-aligned)
  __shared__ float W4ld[4 * 132];       // 2,112 B
  __shared__ signed char adjld[69 * 70];
  for (int idx = tid; idx < 69 * 128; idx += 256) {
    int r = idx >> 7, d = idx & 127;
    hld[r * 132 + d] = h[(b * 69 + r) * 128 + d];
  }
  for (int idx = tid; idx < 512; idx += 256)
    W4ld[(idx >> 7) * 132 + (idx & 127)] = W4[idx];
  for (int idx = tid; idx < NN; idx += 256)
    adjld[(idx / 69) * 70 + (idx % 69)] = (signed char)adj[b * NN + idx];
  __syncthreads();
  for (int t = tid; t < 2415; t += 256) {  // 69*70/2 cells with i<=j
    int a = (int)((sqrtf(8.0f * (float)t + 1.0f) - 1.0f) * 0.5f);
    while ((a + 1) * (a + 2) / 2 <= t) ++a;
    while (a * (a + 1) / 2 > t) --a;
    int i = t - a * (a + 1) / 2;  // i <= j
    int j = a;
    int aij = adjld[i * 70 + j];  // adj[i][j] -> score(row i, col j)
    int aji = adjld[j * 70 + i];  // adj[j][i] -> score(row j, col i)
    float accA = 0.0f, accB = 0.0f;
    if (aij >= 1 || aji >= 1) {
      int ka = (aij >= 1) ? (aij - 1) : 0;
      int kb = (aji >= 1) ? (aji - 1) : 0;
      const float* hi = hld + i * 132;
      const float* hj = hld + j * 132;
      const float* wa = W4ld + ka * 132;
      const float* wb = W4ld + kb * 132;
      #pragma unroll
      for (int d0 = 0; d0 < 128; d0 += 4) {
        float4 x = *(const float4*)(hi + d0);
        float4 y = *(const float4*)(hj + d0);
        float4 u = *(const float4*)(wa + d0);
        float4 v = *(const float4*)(wb + d0);
        float m0 = x.x * y.x, m1 = x.y * y.y, m2 = x.z * y.z, m3 = x.w * y.w;
        accA = fmaf(m0, u.x, accA); accA = fmaf(m1, u.y, accA);
        accA = fmaf(m2, u.z, accA); accA = fmaf(m3, u.w, accA);
        accB = fmaf(m0, v.x, accB); accB = fmaf(m1, v.y, accB);
        accB = fmaf(m2, v.z, accB); accB = fmaf(m3, v.w, accB);
      }
    }
    float sA = (accA >= 0.0f) ? accA : 0.2f * accA;
    float sB = (accB >= 0.0f) ? accB : 0.2f * accB;
    if (aij < 1) sA = NEGV;
    if (aji < 1) sB = NEGV;
    dst[b * NN + i * 69 + j] = sA;
    dst[b * NN + j * 69 + i] = sB;
  }
}

// ---------------- K4: entmax bisection exactly as reference (50 iters, p at final tau_m),
// then w = (pA/sA)*(pB/sB)/(sum+1e-7), written in-place over scA (thread-exclusive row).
__device__ __forceinline__ float pcomp(float xs, float tau, float q) {
  float v = fmaxf(xs - tau, 0.0f);
  return exp2f(q * log2f(v));  // v=0 -> exp2(-inf) = 0
}

__device__ float bisect50(const float (&x)[69], float am1, float q) {
  float mx = -3.0e38f;
  #pragma unroll
  for (int j = 0; j < 69; ++j) mx = fmaxf(mx, x[j]);
  float tau_lo = mx - 1.0f;
  float tau_hi = mx - exp2f(am1 * log2f(1.0f / 69.0f));  // (1/d)^am1
  float dm = tau_hi - tau_lo;
  float tm = tau_lo;
  for (int it = 0; it < 50; ++it) {
    dm *= 0.5f;
    tm = tau_lo + dm;
    float s = 0.0f;
    #pragma unroll
    for (int j = 0; j < 69; ++j) s += pcomp(x[j], tm, q);
    if (s >= 1.0f) tau_lo = tm;
  }
  return tm;  // reference uses the last midpoint tau_m for p
}

__global__ __launch_bounds__(256) void k4_entmax(
    const float* __restrict__ alpha, int o,
    float* __restrict__ scA, const float* __restrict__ scB) {
  const int g = blockIdx.x * 256 + threadIdx.x;  // 70,656 threads exact
  const int b = g / 69, i = g - b * 69;
  const float am1A = alpha[o * 1024 + b];
  const float am1B = alpha[2048 + b];
  const float qA = 1.0f / am1A, qB = 1.0f / am1B;
  float* rowA = scA + b * NN + i * 69;
  const float* rowB = scB + b * NN + i * 69;
  float xa[69], xb[69];
  #pragma unroll
  for (int j = 0; j < 69; ++j) xa[j] = rowA[j] * am1A;
  #pragma unroll
  for (int j = 0; j < 69; ++j) xb[j] = rowB[j] * am1B;
  const float tA = bisect50(xa, am1A, qA);
  const float tB = bisect50(xb, am1B, qB);
  float sA = 0.0f, sB = 0.0f;
  #pragma unroll
  for (int j = 0; j < 69; ++j) { sA += pcomp(xa[j], tA, qA); sB += pcomp(xb[j], tB, qB); }
  const float rsA = 1.0f / sA, rsB = 1.0f / sB;
  float ws = 0.0f;
  #pragma unroll
  for (int j = 0; j < 69; ++j)
    ws += (pcomp(xa[j], tA, qA) * rsA) * (pcomp(xb[j], tB, qB) * rsB);
  const float rden = 1.0f / (ws + 1e-7f);
  #pragma unroll
  for (int j = 0; j < 69; ++j)
    rowA[j] = (pcomp(xa[j], tA, qA) * rsA) * (pcomp(xb[j], tB, qB) * rsB) * rden;
}

// ---------------- K5: out = w @ h (w f32 row-major, h f32, out f32)
__global__ __launch_bounds__(256) void k5_out(
    const float* __restrict__ h, const float* __restrict__ wsrc,
    float* __restrict__ outp) {
  const int b = blockIdx.x, tid = threadIdx.x;
  __shared__ float hld[69 * 132];  // 36,432 B
  __shared__ float wld[69 * 70];   // 19,320 B
  for (int idx = tid; idx < 69 * 128; idx += 256) {
    int r = idx >> 7, d = idx & 127;
    hld[r * 132 + d] = h[(b * 69 + r) * 128 + d];
  }
  for (int idx = tid; idx < NN; idx += 256) {
    int i = idx / 69, j = idx - i * 69;
    wld[i * 70 + j] = wsrc[b * NN + idx];
  }
  __syncthreads();
  for (int s = tid; s < 69 * 32; s += 256) {
    int i = s >> 5, dq = s & 31, d0 = dq << 2;
    float acc0 = 0, acc1 = 0, acc2 = 0, acc3 = 0;
    const float* wrow = wld + i * 70;
    const float* hcol = hld + d0;
    for (int j = 0; j < 69; ++j) {
      float wv = wrow[j];
      float4 hv = *(const float4*)(hcol + j * 132);
      acc0 = fmaf(wv, hv.x, acc0);
      acc1 = fmaf(wv, hv.y, acc1);
      acc2 = fmaf(wv, hv.z, acc2);
      acc3 = fmaf(wv, hv.w, acc3);
    }
    float4 ov = make_float4(acc0, acc1, acc2, acc3);
    *(float4*)(outp + (b * 69 + i) * 128 + d0) = ov;
  }
}

extern "C" void kernel_launch(void* const* d_in, const int* in_sizes, int n_in,
                              void* d_out, int out_size, void* d_ws, size_t ws_size,
                              hipStream_t stream) {
  (void)in_sizes; (void)n_in; (void)out_size;
  // Sf32 36,175,872 | alpha 12,288 | scA 19,501,056 | scB 19,501,056 = 75,190,272 B
  if (ws_size < 75190272u) return;  // early-return signature: absmax == 7.08e-2
  const float* in1 = (const float*)d_in[0];
  const float* in2 = (const float*)d_in[1];
  const float* se  = (const float*)d_in[2];
  const int* adjS  = (const int*)d_in[3];
  const int* adjND = (const int*)d_in[4];
  const float* mask = (const float*)d_in[5];
  const int* iidx  = (const int*)d_in[6];
  const float* Wl  = (const float*)d_in[8];
  const float* bl  = (const float*)d_in[9];
  const float* w1p = (const float*)d_in[10];
  const float* b1p = (const float*)d_in[11];
  const float* w2p = (const float*)d_in[12];
  const float* b2p = (const float*)d_in[13];
  const float* wSp = (const float*)d_in[14];
  const float* bSp = (const float*)d_in[15];
  const float* A1  = (const float*)d_in[16];
  const float* S1  = (const float*)d_in[17];
  const float* A2  = (const float*)d_in[18];
  const float* S2  = (const float*)d_in[19];
  float* Sf    = (float*)d_ws;
  float* alpha = (float*)((char*)d_ws + 36175872);
  float* scA   = (float*)((char*)d_ws + 36188160);
  float* scB   = (float*)((char*)d_ws + 55689216);
  float* outp  = (float*)d_out;

  k1_transform<<<dim3(1024), dim3(256), 0, stream>>>(se, Wl, bl, Sf);
  k2_alpha<<<dim3(1024), dim3(128), 0, stream>>>(in1, in2, Sf, mask, iidx,
                                                 w1p, b1p, w2p, b2p, wSp, bSp, alpha);
  // out1
  k3_scores<<<dim3(1024), dim3(256), 0, stream>>>(in1, A1, adjS, scA);
  k3_scores<<<dim3(1024), dim3(256), 0, stream>>>(Sf,  S1, adjS, scB);
  k4_entmax<<<dim3(276), dim3(256), 0, stream>>>(alpha, 0, scA, scB);
  k5_out<<<dim3(1024), dim3(256), 0, stream>>>(in1, scA, outp);
  // out2
  k3_scores<<<dim3(1024), dim3(256), 0, stream>>>(in2, A2, adjND, scA);
  k3_scores<<<dim3(1024), dim3(256), 0, stream>>>(Sf,  S2, adjND, scB);
  k4_entmax<<<dim3(276), dim3(256), 0, stream>>>(alpha, 1, scA, scB);
  k5_out<<<dim3(1024), dim3(256), 0, stream>>>(in2, scA, outp + SZ_S);
}

// Round 6
// 1032.019 us; speedup vs baseline: 1.1824x; 1.1824x over previous
//
#include <hip/hip_runtime.h>

typedef unsigned int uint;
typedef unsigned short ushort;

#define NN 4761            // 69*69
#define SZ_S 9043968       // 1024*69*128
#define NEGV -9000000.0f

// ---------------- K1: S = structure_embed @ W_lin^T + b_lin (all f32)
// Block per batch. Thread i (=tid&127) owns output column i, W row i in registers.
__global__ __launch_bounds__(256) void k1_transform(
    const float* __restrict__ se, const float* __restrict__ Wl,
    const float* __restrict__ bl, float* __restrict__ S) {
  __shared__ float seld[69 * 128];  // 35,328 B
  const int tid = threadIdx.x, b = blockIdx.x;
  const int rr = tid >> 7, i = tid & 127;
  float w[128];
  #pragma unroll
  for (int d0 = 0; d0 < 128; d0 += 4) {
    float4 v = *(const float4*)(Wl + i * 128 + d0);
    w[d0] = v.x; w[d0 + 1] = v.y; w[d0 + 2] = v.z; w[d0 + 3] = v.w;
  }
  for (int idx = tid; idx < 69 * 128; idx += 256) seld[idx] = se[b * 69 * 128 + idx];
  __syncthreads();
  const float bias = bl[i];
  for (int k = 0; k < 35; ++k) {
    int r = 2 * k + rr;
    if (r < 69) {
      float acc = bias;
      #pragma unroll
      for (int d0 = 0; d0 < 128; d0 += 4) {
        float4 sv = *(const float4*)(seld + r * 128 + d0);
        acc = fmaf(sv.x, w[d0], acc);
        acc = fmaf(sv.y, w[d0 + 1], acc);
        acc = fmaf(sv.z, w[d0 + 2], acc);
        acc = fmaf(sv.w, w[d0 + 3], acc);
      }
      S[(b * 69 + r) * 128 + i] = acc;
    }
  }
}

// ---------------- K2: alphas (stores am1 = alpha-1): [0..1023]=sem1, [1024..]=sem2, [2048..]=str
__global__ __launch_bounds__(128) void k2_alpha(
    const float* __restrict__ in1, const float* __restrict__ in2,
    const float* __restrict__ S, const float* __restrict__ mask,
    const int* __restrict__ iidx,
    const float* __restrict__ w1p, const float* __restrict__ b1p,
    const float* __restrict__ w2p, const float* __restrict__ b2p,
    const float* __restrict__ wSp, const float* __restrict__ bSp,
    float* __restrict__ alpha) {
  __shared__ float red[3][2];
  const int b = blockIdx.x, d = threadIdx.x;
  const int last = iidx[b * 69 + 68];
  float a1 = 0, a2 = 0, aS = 0, am = 0;
  const float* p1 = in1 + b * 69 * 128 + d;
  const float* p2 = in2 + b * 69 * 128 + d;
  const float* pS = S + b * 69 * 128 + d;
  const float* pm = mask + b * 69;
  for (int n = 0; n < 69; ++n) {
    float m = pm[n];
    a1 += p1[n * 128] * m;
    a2 += p2[n * 128] * m;
    aS += pS[n * 128] * m;
    am += m;
  }
  float z1 = (a1 / am + p1[last * 128]) * w1p[d];
  float z2 = (a2 / am + p2[last * 128]) * w2p[d];
  float zS = (aS / am + pS[last * 128]) * wSp[d];
  for (int off = 32; off >= 1; off >>= 1) {
    z1 += __shfl_down(z1, off);
    z2 += __shfl_down(z2, off);
    zS += __shfl_down(zS, off);
  }
  if ((d & 63) == 0) { int wv = d >> 6; red[0][wv] = z1; red[1][wv] = z2; red[2][wv] = zS; }
  __syncthreads();
  if (d == 0) {
    float r1 = 1.0f / (1.0f + expf(-(red[0][0] + red[0][1] + b1p[0]))) + 1.0f;
    float r2 = 1.0f / (1.0f + expf(-(red[1][0] + red[1][1] + b2p[0]))) + 1.0f;
    float rS = 1.0f / (1.0f + expf(-(red[2][0] + red[2][1] + bSp[0]))) + 1.0f;
    if (r1 == 1.0f) r1 = 1.0001f;
    if (r2 == 1.0f) r2 = 1.0001f;
    if (rS == 1.0f) rS = 1.0001f;
    alpha[b] = r1 - 1.0f;
    alpha[1024 + b] = r2 - 1.0f;
    alpha[2048 + b] = rS - 1.0f;
  }
}

// ---------------- K3: masked leaky scores, one (h, W4, adj) triple per launch.
// dst[b][i][j] f32, row-major. Upper-tri cells (i<=j): shared symmetric dot, per-side k/mask.
__global__ __launch_bounds__(256) void k3_scores(
    const float* __restrict__ h, const float* __restrict__ W4,
    const int* __restrict__ adj, float* __restrict__ dst) {
  const int b = blockIdx.x, tid = threadIdx.x;
  __shared__ float hld[69 * 132];       // 36,432 B (pad 132: bank spread, 16B-aligned)
  __shared__ float W4ld[4 * 132];       // 2,112 B
  __shared__ signed char adjld[69 * 70];
  for (int idx = tid; idx < 69 * 128; idx += 256) {
    int r = idx >> 7, d = idx & 127;
    hld[r * 132 + d] = h[(b * 69 + r) * 128 + d];
  }
  for (int idx = tid; idx < 512; idx += 256)
    W4ld[(idx >> 7) * 132 + (idx & 127)] = W4[idx];
  for (int idx = tid; idx < NN; idx += 256)
    adjld[(idx / 69) * 70 + (idx % 69)] = (signed char)adj[b * NN + idx];
  __syncthreads();
  for (int t = tid; t < 2415; t += 256) {  // 69*70/2 cells with i<=j
    int a = (int)((sqrtf(8.0f * (float)t + 1.0f) - 1.0f) * 0.5f);
    while ((a + 1) * (a + 2) / 2 <= t) ++a;
    while (a * (a + 1) / 2 > t) --a;
    int i = t - a * (a + 1) / 2;  // i <= j
    int j = a;
    int aij = adjld[i * 70 + j];  // adj[i][j] -> score(row i, col j)
    int aji = adjld[j * 70 + i];  // adj[j][i] -> score(row j, col i)
    float accA = 0.0f, accB = 0.0f;
    if (aij >= 1 || aji >= 1) {
      int ka = (aij >= 1) ? (aij - 1) : 0;
      int kb = (aji >= 1) ? (aji - 1) : 0;
      const float* hi = hld + i * 132;
      const float* hj = hld + j * 132;
      const float* wa = W4ld + ka * 132;
      const float* wb = W4ld + kb * 132;
      #pragma unroll
      for (int d0 = 0; d0 < 128; d0 += 4) {
        float4 x = *(const float4*)(hi + d0);
        float4 y = *(const float4*)(hj + d0);
        float4 u = *(const float4*)(wa + d0);
        float4 v = *(const float4*)(wb + d0);
        float m0 = x.x * y.x, m1 = x.y * y.y, m2 = x.z * y.z, m3 = x.w * y.w;
        accA = fmaf(m0, u.x, accA); accA = fmaf(m1, u.y, accA);
        accA = fmaf(m2, u.z, accA); accA = fmaf(m3, u.w, accA);
        accB = fmaf(m0, v.x, accB); accB = fmaf(m1, v.y, accB);
        accB = fmaf(m2, v.z, accB); accB = fmaf(m3, v.w, accB);
      }
    }
    float sA = (accA >= 0.0f) ? accA : 0.2f * accA;
    float sB = (accB >= 0.0f) ? accB : 0.2f * accB;
    if (aij < 1) sA = NEGV;
    if (aji < 1) sB = NEGV;
    dst[b * NN + i * 69 + j] = sA;
    dst[b * NN + j * 69 + i] = sB;
  }
}

// ---------------- K4: entmax bisection, spill-free: one 69-reg array, sides sequential.
// 34 iters == reference's 50 in f32 (dm_34 <= 2^-34; tau delta ~6e-11 << tolerance).
__device__ __forceinline__ float pcomp(float xs, float tau, float q) {
  float v = fmaxf(xs - tau, 0.0f);
  return exp2f(q * log2f(v));  // v=0 -> exp2(-inf) = 0
}

__device__ __forceinline__ float bisect34(const float (&x)[69], float am1, float q) {
  float mx = -3.0e38f;
  #pragma unroll
  for (int j = 0; j < 69; ++j) mx = fmaxf(mx, x[j]);
  float tau_lo = mx - 1.0f;
  float tau_hi = mx - exp2f(am1 * log2f(1.0f / 69.0f));  // (1/d)^am1
  float dm = tau_hi - tau_lo;
  float tm = tau_lo;
  #pragma unroll 1
  for (int it = 0; it < 34; ++it) {
    dm *= 0.5f;
    tm = tau_lo + dm;
    float s = 0.0f;
    #pragma unroll
    for (int j = 0; j < 69; ++j) s += pcomp(x[j], tm, q);
    if (s >= 1.0f) tau_lo = tm;
  }
  return tm;  // reference uses the last midpoint tau_m for p
}

__global__ __launch_bounds__(256, 1) void k4_entmax(
    const float* __restrict__ alpha, int o,
    float* __restrict__ scA, const float* __restrict__ scB) {
  const int g = blockIdx.x * 256 + threadIdx.x;  // 70,656 threads exact
  const int b = g / 69, i = g - b * 69;
  const float am1A = alpha[o * 1024 + b];
  const float am1B = alpha[2048 + b];
  float* rowA = scA + b * NN + i * 69;
  const float* rowB = scB + b * NN + i * 69;
  float x[69];
  // ---- side A: bisect, normalize, park pA_norm in rowA
  const float qA = 1.0f / am1A;
  #pragma unroll
  for (int j = 0; j < 69; ++j) x[j] = rowA[j] * am1A;
  const float tA = bisect34(x, am1A, qA);
  float sA = 0.0f;
  #pragma unroll
  for (int j = 0; j < 69; ++j) { x[j] = pcomp(x[j], tA, qA); sA += x[j]; }
  const float rsA = 1.0f / sA;
  #pragma unroll
  for (int j = 0; j < 69; ++j) rowA[j] = x[j] * rsA;
  // ---- side B: bisect in the SAME registers, then combine with parked pA_norm
  const float qB = 1.0f / am1B;
  #pragma unroll
  for (int j = 0; j < 69; ++j) x[j] = rowB[j] * am1B;
  const float tB = bisect34(x, am1B, qB);
  float sB = 0.0f;
  #pragma unroll
  for (int j = 0; j < 69; ++j) { x[j] = pcomp(x[j], tB, qB); sB += x[j]; }
  const float rsB = 1.0f / sB;
  float ws = 0.0f;
  #pragma unroll
  for (int j = 0; j < 69; ++j) { x[j] = rowA[j] * (x[j] * rsB); ws += x[j]; }
  const float rden = 1.0f / (ws + 1e-7f);
  #pragma unroll
  for (int j = 0; j < 69; ++j) rowA[j] = x[j] * rden;
}

// ---------------- K5: out = w @ h (w f32 row-major, h f32, out f32)
__global__ __launch_bounds__(256) void k5_out(
    const float* __restrict__ h, const float* __restrict__ wsrc,
    float* __restrict__ outp) {
  const int b = blockIdx.x, tid = threadIdx.x;
  __shared__ float hld[69 * 132];  // 36,432 B
  __shared__ float wld[69 * 70];   // 19,320 B
  for (int idx = tid; idx < 69 * 128; idx += 256) {
    int r = idx >> 7, d = idx & 127;
    hld[r * 132 + d] = h[(b * 69 + r) * 128 + d];
  }
  for (int idx = tid; idx < NN; idx += 256) {
    int i = idx / 69, j = idx - i * 69;
    wld[i * 70 + j] = wsrc[b * NN + idx];
  }
  __syncthreads();
  for (int s = tid; s < 69 * 32; s += 256) {
    int i = s >> 5, dq = s & 31, d0 = dq << 2;
    float acc0 = 0, acc1 = 0, acc2 = 0, acc3 = 0;
    const float* wrow = wld + i * 70;
    const float* hcol = hld + d0;
    for (int j = 0; j < 69; ++j) {
      float wv = wrow[j];
      float4 hv = *(const float4*)(hcol + j * 132);
      acc0 = fmaf(wv, hv.x, acc0);
      acc1 = fmaf(wv, hv.y, acc1);
      acc2 = fmaf(wv, hv.z, acc2);
      acc3 = fmaf(wv, hv.w, acc3);
    }
    float4 ov = make_float4(acc0, acc1, acc2, acc3);
    *(float4*)(outp + (b * 69 + i) * 128 + d0) = ov;
  }
}

extern "C" void kernel_launch(void* const* d_in, const int* in_sizes, int n_in,
                              void* d_out, int out_size, void* d_ws, size_t ws_size,
                              hipStream_t stream) {
  (void)in_sizes; (void)n_in; (void)out_size;
  // Sf32 36,175,872 | alpha 12,288 | scA 19,501,056 | scB 19,501,056 = 75,190,272 B
  if (ws_size < 75190272u) return;  // early-return signature: absmax == 7.08e-2
  const float* in1 = (const float*)d_in[0];
  const float* in2 = (const float*)d_in[1];
  const float* se  = (const float*)d_in[2];
  const int* adjS  = (const int*)d_in[3];
  const int* adjND = (const int*)d_in[4];
  const float* mask = (const float*)d_in[5];
  const int* iidx  = (const int*)d_in[6];
  const float* Wl  = (const float*)d_in[8];
  const float* bl  = (const float*)d_in[9];
  const float* w1p = (const float*)d_in[10];
  const float* b1p = (const float*)d_in[11];
  const float* w2p = (const float*)d_in[12];
  const float* b2p = (const float*)d_in[13];
  const float* wSp = (const float*)d_in[14];
  const float* bSp = (const float*)d_in[15];
  const float* A1  = (const float*)d_in[16];
  const float* S1  = (const float*)d_in[17];
  const float* A2  = (const float*)d_in[18];
  const float* S2  = (const float*)d_in[19];
  float* Sf    = (float*)d_ws;
  float* alpha = (float*)((char*)d_ws + 36175872);
  float* scA   = (float*)((char*)d_ws + 36188160);
  float* scB   = (float*)((char*)d_ws + 55689216);
  float* outp  = (float*)d_out;

  k1_transform<<<dim3(1024), dim3(256), 0, stream>>>(se, Wl, bl, Sf);
  k2_alpha<<<dim3(1024), dim3(128), 0, stream>>>(in1, in2, Sf, mask, iidx,
                                                 w1p, b1p, w2p, b2p, wSp, bSp, alpha);
  // out1
  k3_scores<<<dim3(1024), dim3(256), 0, stream>>>(in1, A1, adjS, scA);
  k3_scores<<<dim3(1024), dim3(256), 0, stream>>>(Sf,  S1, adjS, scB);
  k4_entmax<<<dim3(276), dim3(256), 0, stream>>>(alpha, 0, scA, scB);
  k5_out<<<dim3(1024), dim3(256), 0, stream>>>(in1, scA, outp);
  // out2
  k3_scores<<<dim3(1024), dim3(256), 0, stream>>>(in2, A2, adjND, scA);
  k3_scores<<<dim3(1024), dim3(256), 0, stream>>>(Sf,  S2, adjND, scB);
  k4_entmax<<<dim3(276), dim3(256), 0, stream>>>(alpha, 1, scA, scB);
  k5_out<<<dim3(1024), dim3(256), 0, stream>>>(in2, scA, outp + SZ_S);
}

// Round 7
// 800.018 us; speedup vs baseline: 1.5252x; 1.2900x over previous
//
#include <hip/hip_runtime.h>

typedef unsigned int uint;
typedef unsigned short ushort;

#define NN 4761            // 69*69
#define SZ_S 9043968       // 1024*69*128
#define NEGV -9000000.0f

// ---------------- K1: S = structure_embed @ W_lin^T + b_lin (all f32)
// Block per batch. Thread i (=tid&127) owns output column i, W row i in registers.
__global__ __launch_bounds__(256) void k1_transform(
    const float* __restrict__ se, const float* __restrict__ Wl,
    const float* __restrict__ bl, float* __restrict__ S) {
  __shared__ float seld[69 * 128];  // 35,328 B
  const int tid = threadIdx.x, b = blockIdx.x;
  const int rr = tid >> 7, i = tid & 127;
  float w[128];
  #pragma unroll
  for (int d0 = 0; d0 < 128; d0 += 4) {
    float4 v = *(const float4*)(Wl + i * 128 + d0);
    w[d0] = v.x; w[d0 + 1] = v.y; w[d0 + 2] = v.z; w[d0 + 3] = v.w;
  }
  for (int idx = tid; idx < 69 * 128; idx += 256) seld[idx] = se[b * 69 * 128 + idx];
  __syncthreads();
  const float bias = bl[i];
  for (int k = 0; k < 35; ++k) {
    int r = 2 * k + rr;
    if (r < 69) {
      float acc = bias;
      #pragma unroll
      for (int d0 = 0; d0 < 128; d0 += 4) {
        float4 sv = *(const float4*)(seld + r * 128 + d0);
        acc = fmaf(sv.x, w[d0], acc);
        acc = fmaf(sv.y, w[d0 + 1], acc);
        acc = fmaf(sv.z, w[d0 + 2], acc);
        acc = fmaf(sv.w, w[d0 + 3], acc);
      }
      S[(b * 69 + r) * 128 + i] = acc;
    }
  }
}

// ---------------- K2: alphas (stores am1 = alpha-1): [0..1023]=sem1, [1024..]=sem2, [2048..]=str
__global__ __launch_bounds__(128) void k2_alpha(
    const float* __restrict__ in1, const float* __restrict__ in2,
    const float* __restrict__ S, const float* __restrict__ mask,
    const int* __restrict__ iidx,
    const float* __restrict__ w1p, const float* __restrict__ b1p,
    const float* __restrict__ w2p, const float* __restrict__ b2p,
    const float* __restrict__ wSp, const float* __restrict__ bSp,
    float* __restrict__ alpha) {
  __shared__ float red[3][2];
  const int b = blockIdx.x, d = threadIdx.x;
  const int last = iidx[b * 69 + 68];
  float a1 = 0, a2 = 0, aS = 0, am = 0;
  const float* p1 = in1 + b * 69 * 128 + d;
  const float* p2 = in2 + b * 69 * 128 + d;
  const float* pS = S + b * 69 * 128 + d;
  const float* pm = mask + b * 69;
  for (int n = 0; n < 69; ++n) {
    float m = pm[n];
    a1 += p1[n * 128] * m;
    a2 += p2[n * 128] * m;
    aS += pS[n * 128] * m;
    am += m;
  }
  float z1 = (a1 / am + p1[last * 128]) * w1p[d];
  float z2 = (a2 / am + p2[last * 128]) * w2p[d];
  float zS = (aS / am + pS[last * 128]) * wSp[d];
  for (int off = 32; off >= 1; off >>= 1) {
    z1 += __shfl_down(z1, off);
    z2 += __shfl_down(z2, off);
    zS += __shfl_down(zS, off);
  }
  if ((d & 63) == 0) { int wv = d >> 6; red[0][wv] = z1; red[1][wv] = z2; red[2][wv] = zS; }
  __syncthreads();
  if (d == 0) {
    float r1 = 1.0f / (1.0f + expf(-(red[0][0] + red[0][1] + b1p[0]))) + 1.0f;
    float r2 = 1.0f / (1.0f + expf(-(red[1][0] + red[1][1] + b2p[0]))) + 1.0f;
    float rS = 1.0f / (1.0f + expf(-(red[2][0] + red[2][1] + bSp[0]))) + 1.0f;
    if (r1 == 1.0f) r1 = 1.0001f;
    if (r2 == 1.0f) r2 = 1.0001f;
    if (rS == 1.0f) rS = 1.0001f;
    alpha[b] = r1 - 1.0f;
    alpha[1024 + b] = r2 - 1.0f;
    alpha[2048 + b] = rS - 1.0f;
  }
}

// ---------------- K3: masked leaky scores, one (h, W4, adj) triple per launch.
// dst[b][i][j] f32, row-major. Upper-tri cells (i<=j): shared symmetric dot, per-side k/mask.
__global__ __launch_bounds__(256) void k3_scores(
    const float* __restrict__ h, const float* __restrict__ W4,
    const int* __restrict__ adj, float* __restrict__ dst) {
  const int b = blockIdx.x, tid = threadIdx.x;
  __shared__ float hld[69 * 132];       // 36,432 B (pad 132: bank spread, 16B-aligned)
  __shared__ float W4ld[4 * 132];       // 2,112 B
  __shared__ signed char adjld[69 * 70];
  for (int idx = tid; idx < 69 * 128; idx += 256) {
    int r = idx >> 7, d = idx & 127;
    hld[r * 132 + d] = h[(b * 69 + r) * 128 + d];
  }
  for (int idx = tid; idx < 512; idx += 256)
    W4ld[(idx >> 7) * 132 + (idx & 127)] = W4[idx];
  for (int idx = tid; idx < NN; idx += 256)
    adjld[(idx / 69) * 70 + (idx % 69)] = (signed char)adj[b * NN + idx];
  __syncthreads();
  for (int t = tid; t < 2415; t += 256) {  // 69*70/2 cells with i<=j
    int a = (int)((sqrtf(8.0f * (float)t + 1.0f) - 1.0f) * 0.5f);
    while ((a + 1) * (a + 2) / 2 <= t) ++a;
    while (a * (a + 1) / 2 > t) --a;
    int i = t - a * (a + 1) / 2;  // i <= j
    int j = a;
    int aij = adjld[i * 70 + j];  // adj[i][j] -> score(row i, col j)
    int aji = adjld[j * 70 + i];  // adj[j][i] -> score(row j, col i)
    float accA = 0.0f, accB = 0.0f;
    if (aij >= 1 || aji >= 1) {
      int ka = (aij >= 1) ? (aij - 1) : 0;
      int kb = (aji >= 1) ? (aji - 1) : 0;
      const float* hi = hld + i * 132;
      const float* hj = hld + j * 132;
      const float* wa = W4ld + ka * 132;
      const float* wb = W4ld + kb * 132;
      #pragma unroll
      for (int d0 = 0; d0 < 128; d0 += 4) {
        float4 x = *(const float4*)(hi + d0);
        float4 y = *(const float4*)(hj + d0);
        float4 u = *(const float4*)(wa + d0);
        float4 v = *(const float4*)(wb + d0);
        float m0 = x.x * y.x, m1 = x.y * y.y, m2 = x.z * y.z, m3 = x.w * y.w;
        accA = fmaf(m0, u.x, accA); accA = fmaf(m1, u.y, accA);
        accA = fmaf(m2, u.z, accA); accA = fmaf(m3, u.w, accA);
        accB = fmaf(m0, v.x, accB); accB = fmaf(m1, v.y, accB);
        accB = fmaf(m2, v.z, accB); accB = fmaf(m3, v.w, accB);
      }
    }
    float sA = (accA >= 0.0f) ? accA : 0.2f * accA;
    float sB = (accB >= 0.0f) ? accB : 0.2f * accB;
    if (aij < 1) sA = NEGV;
    if (aji < 1) sB = NEGV;
    dst[b * NN + i * 69 + j] = sA;
    dst[b * NN + j * 69 + i] = sB;
  }
}

// ---------------- K4: entmax, 16-lanes-per-row (wave = 4 rows). Element j of a row lives in
// lane j%16, slot j/16 -> 5 VGPRs of row state; row-sum = 4-step shfl_xor butterfly (width 16).
// p_A kept in registers across side B; single final write. 34 iters == reference's 50 in f32.
__device__ __forceinline__ float pcomp(float xs, float tau, float q) {
  float v = fmaxf(xs - tau, 0.0f);
  return exp2f(q * log2f(v));  // v=0 -> exp2(-inf) = 0
}

__device__ __forceinline__ float gsum16(float s) {
  #pragma unroll
  for (int d = 1; d < 16; d <<= 1) s += __shfl_xor(s, d, 16);
  return s;
}

__device__ __forceinline__ float bisect34w(const float (&x)[5], float am1, float q) {
  float mx = fmaxf(fmaxf(fmaxf(x[0], x[1]), fmaxf(x[2], x[3])), x[4]);
  #pragma unroll
  for (int d = 1; d < 16; d <<= 1) mx = fmaxf(mx, __shfl_xor(mx, d, 16));
  float tau_lo = mx - 1.0f;
  float tau_hi = mx - exp2f(am1 * log2f(1.0f / 69.0f));  // (1/d)^am1
  float dm = tau_hi - tau_lo;
  float tm = tau_lo;
  #pragma unroll 1
  for (int it = 0; it < 34; ++it) {
    dm *= 0.5f;
    tm = tau_lo + dm;
    float s = pcomp(x[0], tm, q) + pcomp(x[1], tm, q) + pcomp(x[2], tm, q) +
              pcomp(x[3], tm, q) + pcomp(x[4], tm, q);
    s = gsum16(s);
    if (s >= 1.0f) tau_lo = tm;  // uniform within the 16-lane group
  }
  return tm;  // reference uses the last midpoint tau_m for p
}

__global__ __launch_bounds__(256) void k4_entmax(
    const float* __restrict__ alpha, int o,
    float* __restrict__ scA, const float* __restrict__ scB) {
  const int tid = threadIdx.x;
  const int wave = tid >> 6, lane = tid & 63;
  const int grp = lane >> 4, l16 = lane & 15;
  const int row = blockIdx.x * 16 + wave * 4 + grp;  // 0..70655 (4416 blocks)
  const int b = row / 69;
  const float am1A = alpha[o * 1024 + b];
  const float am1B = alpha[2048 + b];
  float* rowA = scA + 69u * (uint)row;
  const float* rowB = scB + 69u * (uint)row;
  // ---- side A
  const float qA = 1.0f / am1A;
  float x[5], pa[5];
  #pragma unroll
  for (int s = 0; s < 5; ++s) {
    int j = s * 16 + l16;
    x[s] = (j < 69) ? rowA[j] * am1A : -1.0e30f;  // pad -> v=0 -> p=0
  }
  const float tA = bisect34w(x, am1A, qA);
  float sA = 0.0f;
  #pragma unroll
  for (int s = 0; s < 5; ++s) { pa[s] = pcomp(x[s], tA, qA); sA += pa[s]; }
  sA = gsum16(sA);
  const float rsA = 1.0f / sA;
  // ---- side B (reuse x registers)
  const float qB = 1.0f / am1B;
  #pragma unroll
  for (int s = 0; s < 5; ++s) {
    int j = s * 16 + l16;
    x[s] = (j < 69) ? rowB[j] * am1B : -1.0e30f;
  }
  const float tB = bisect34w(x, am1B, qB);
  float sB = 0.0f;
  #pragma unroll
  for (int s = 0; s < 5; ++s) { x[s] = pcomp(x[s], tB, qB); sB += x[s]; }
  sB = gsum16(sB);
  const float rsB = 1.0f / sB;
  // ---- combine: w = (pA/sA)*(pB/sB) / (sum + 1e-7)
  float ws = 0.0f;
  #pragma unroll
  for (int s = 0; s < 5; ++s) { x[s] = (pa[s] * rsA) * (x[s] * rsB); ws += x[s]; }
  ws = gsum16(ws);
  const float rden = 1.0f / (ws + 1e-7f);
  #pragma unroll
  for (int s = 0; s < 5; ++s) {
    int j = s * 16 + l16;
    if (j < 69) rowA[j] = x[s] * rden;
  }
}

// ---------------- K5: out = w @ h (w f32 row-major, h f32, out f32)
__global__ __launch_bounds__(256) void k5_out(
    const float* __restrict__ h, const float* __restrict__ wsrc,
    float* __restrict__ outp) {
  const int b = blockIdx.x, tid = threadIdx.x;
  __shared__ float hld[69 * 132];  // 36,432 B
  __shared__ float wld[69 * 70];   // 19,320 B
  for (int idx = tid; idx < 69 * 128; idx += 256) {
    int r = idx >> 7, d = idx & 127;
    hld[r * 132 + d] = h[(b * 69 + r) * 128 + d];
  }
  for (int idx = tid; idx < NN; idx += 256) {
    int i = idx / 69, j = idx - i * 69;
    wld[i * 70 + j] = wsrc[b * NN + idx];
  }
  __syncthreads();
  for (int s = tid; s < 69 * 32; s += 256) {
    int i = s >> 5, dq = s & 31, d0 = dq << 2;
    float acc0 = 0, acc1 = 0, acc2 = 0, acc3 = 0;
    const float* wrow = wld + i * 70;
    const float* hcol = hld + d0;
    for (int j = 0; j < 69; ++j) {
      float wv = wrow[j];
      float4 hv = *(const float4*)(hcol + j * 132);
      acc0 = fmaf(wv, hv.x, acc0);
      acc1 = fmaf(wv, hv.y, acc1);
      acc2 = fmaf(wv, hv.z, acc2);
      acc3 = fmaf(wv, hv.w, acc3);
    }
    float4 ov = make_float4(acc0, acc1, acc2, acc3);
    *(float4*)(outp + (b * 69 + i) * 128 + d0) = ov;
  }
}

extern "C" void kernel_launch(void* const* d_in, const int* in_sizes, int n_in,
                              void* d_out, int out_size, void* d_ws, size_t ws_size,
                              hipStream_t stream) {
  (void)in_sizes; (void)n_in; (void)out_size;
  // Sf32 36,175,872 | alpha 12,288 | scA 19,501,056 | scB 19,501,056 = 75,190,272 B
  if (ws_size < 75190272u) return;  // early-return signature: absmax == 7.08e-2
  const float* in1 = (const float*)d_in[0];
  const float* in2 = (const float*)d_in[1];
  const float* se  = (const float*)d_in[2];
  const int* adjS  = (const int*)d_in[3];
  const int* adjND = (const int*)d_in[4];
  const float* mask = (const float*)d_in[5];
  const int* iidx  = (const int*)d_in[6];
  const float* Wl  = (const float*)d_in[8];
  const float* bl  = (const float*)d_in[9];
  const float* w1p = (const float*)d_in[10];
  const float* b1p = (const float*)d_in[11];
  const float* w2p = (const float*)d_in[12];
  const float* b2p = (const float*)d_in[13];
  const float* wSp = (const float*)d_in[14];
  const float* bSp = (const float*)d_in[15];
  const float* A1  = (const float*)d_in[16];
  const float* S1  = (const float*)d_in[17];
  const float* A2  = (const float*)d_in[18];
  const float* S2  = (const float*)d_in[19];
  float* Sf    = (float*)d_ws;
  float* alpha = (float*)((char*)d_ws + 36175872);
  float* scA   = (float*)((char*)d_ws + 36188160);
  float* scB   = (float*)((char*)d_ws + 55689216);
  float* outp  = (float*)d_out;

  k1_transform<<<dim3(1024), dim3(256), 0, stream>>>(se, Wl, bl, Sf);
  k2_alpha<<<dim3(1024), dim3(128), 0, stream>>>(in1, in2, Sf, mask, iidx,
                                                 w1p, b1p, w2p, b2p, wSp, bSp, alpha);
  // out1
  k3_scores<<<dim3(1024), dim3(256), 0, stream>>>(in1, A1, adjS, scA);
  k3_scores<<<dim3(1024), dim3(256), 0, stream>>>(Sf,  S1, adjS, scB);
  k4_entmax<<<dim3(4416), dim3(256), 0, stream>>>(alpha, 0, scA, scB);
  k5_out<<<dim3(1024), dim3(256), 0, stream>>>(in1, scA, outp);
  // out2
  k3_scores<<<dim3(1024), dim3(256), 0, stream>>>(in2, A2, adjND, scA);
  k3_scores<<<dim3(1024), dim3(256), 0, stream>>>(Sf,  S2, adjND, scB);
  k4_entmax<<<dim3(4416), dim3(256), 0, stream>>>(alpha, 1, scA, scB);
  k5_out<<<dim3(1024), dim3(256), 0, stream>>>(in2, scA, outp + SZ_S);
}

// Round 8
// 599.515 us; speedup vs baseline: 2.0353x; 1.3344x over previous
//
#include <hip/hip_runtime.h>

typedef unsigned int uint;
typedef unsigned short ushort;

#define NN 4761            // 69*69
#define SZ_S 9043968       // 1024*69*128
#define NEGV -9000000.0f

// Native single-instruction transcendentals (base-2). Pure asm (no volatile) so the
// scheduler can move them. v_log_f32(0) = -inf, v_exp_f32(-inf) = 0 -> masked
// elements produce p = 0 exactly, same as the OCML path.
__device__ __forceinline__ float fexp2(float x) {
  float r; asm("v_exp_f32 %0, %1" : "=v"(r) : "v"(x)); return r;
}
__device__ __forceinline__ float flog2(float x) {
  float r; asm("v_log_f32 %0, %1" : "=v"(r) : "v"(x)); return r;
}

// ---------------- K1: S = structure_embed @ W_lin^T + b_lin (all f32)
__global__ __launch_bounds__(256) void k1_transform(
    const float* __restrict__ se, const float* __restrict__ Wl,
    const float* __restrict__ bl, float* __restrict__ S) {
  __shared__ float seld[69 * 128];  // 35,328 B
  const int tid = threadIdx.x, b = blockIdx.x;
  const int rr = tid >> 7, i = tid & 127;
  float w[128];
  #pragma unroll
  for (int d0 = 0; d0 < 128; d0 += 4) {
    float4 v = *(const float4*)(Wl + i * 128 + d0);
    w[d0] = v.x; w[d0 + 1] = v.y; w[d0 + 2] = v.z; w[d0 + 3] = v.w;
  }
  for (int idx = tid; idx < 69 * 128; idx += 256) seld[idx] = se[b * 69 * 128 + idx];
  __syncthreads();
  const float bias = bl[i];
  for (int k = 0; k < 35; ++k) {
    int r = 2 * k + rr;
    if (r < 69) {
      float acc = bias;
      #pragma unroll
      for (int d0 = 0; d0 < 128; d0 += 4) {
        float4 sv = *(const float4*)(seld + r * 128 + d0);
        acc = fmaf(sv.x, w[d0], acc);
        acc = fmaf(sv.y, w[d0 + 1], acc);
        acc = fmaf(sv.z, w[d0 + 2], acc);
        acc = fmaf(sv.w, w[d0 + 3], acc);
      }
      S[(b * 69 + r) * 128 + i] = acc;
    }
  }
}

// ---------------- K2: alphas (stores am1 = alpha-1): [0..1023]=sem1, [1024..]=sem2, [2048..]=str
__global__ __launch_bounds__(128) void k2_alpha(
    const float* __restrict__ in1, const float* __restrict__ in2,
    const float* __restrict__ S, const float* __restrict__ mask,
    const int* __restrict__ iidx,
    const float* __restrict__ w1p, const float* __restrict__ b1p,
    const float* __restrict__ w2p, const float* __restrict__ b2p,
    const float* __restrict__ wSp, const float* __restrict__ bSp,
    float* __restrict__ alpha) {
  __shared__ float red[3][2];
  const int b = blockIdx.x, d = threadIdx.x;
  const int last = iidx[b * 69 + 68];
  float a1 = 0, a2 = 0, aS = 0, am = 0;
  const float* p1 = in1 + b * 69 * 128 + d;
  const float* p2 = in2 + b * 69 * 128 + d;
  const float* pS = S + b * 69 * 128 + d;
  const float* pm = mask + b * 69;
  for (int n = 0; n < 69; ++n) {
    float m = pm[n];
    a1 += p1[n * 128] * m;
    a2 += p2[n * 128] * m;
    aS += pS[n * 128] * m;
    am += m;
  }
  float z1 = (a1 / am + p1[last * 128]) * w1p[d];
  float z2 = (a2 / am + p2[last * 128]) * w2p[d];
  float zS = (aS / am + pS[last * 128]) * wSp[d];
  for (int off = 32; off >= 1; off >>= 1) {
    z1 += __shfl_down(z1, off);
    z2 += __shfl_down(z2, off);
    zS += __shfl_down(zS, off);
  }
  if ((d & 63) == 0) { int wv = d >> 6; red[0][wv] = z1; red[1][wv] = z2; red[2][wv] = zS; }
  __syncthreads();
  if (d == 0) {
    float r1 = 1.0f / (1.0f + expf(-(red[0][0] + red[0][1] + b1p[0]))) + 1.0f;
    float r2 = 1.0f / (1.0f + expf(-(red[1][0] + red[1][1] + b2p[0]))) + 1.0f;
    float rS = 1.0f / (1.0f + expf(-(red[2][0] + red[2][1] + bSp[0]))) + 1.0f;
    if (r1 == 1.0f) r1 = 1.0001f;
    if (r2 == 1.0f) r2 = 1.0001f;
    if (rS == 1.0f) rS = 1.0001f;
    alpha[b] = r1 - 1.0f;
    alpha[1024 + b] = r2 - 1.0f;
    alpha[2048 + b] = rS - 1.0f;
  }
}

// ---------------- K3: masked leaky scores. grid(1024, 2): y selects the (h, W4, dst) triple
// (adj shared). 2x2 row-pair tiles: one symmetric dot (all 4 k's) serves 4 cells x 2
// orientations -> LDS traffic per cell halved vs per-cell version.
__global__ __launch_bounds__(256) void k3_scores(
    const float* __restrict__ hA, const float* __restrict__ W4A, float* __restrict__ dstA,
    const float* __restrict__ hB, const float* __restrict__ W4B, float* __restrict__ dstB,
    const int* __restrict__ adj) {
  const int b = blockIdx.x, tid = threadIdx.x;
  const float* h  = blockIdx.y ? hB : hA;
  const float* W4 = blockIdx.y ? W4B : W4A;
  float* dst      = blockIdx.y ? dstB : dstA;
  __shared__ float hld[69 * 132];       // 36,432 B
  __shared__ float W4ld[4 * 132];       // 2,112 B
  __shared__ signed char adjld[69 * 70];
  for (int idx = tid; idx < 69 * 128; idx += 256) {
    int r = idx >> 7, d = idx & 127;
    hld[r * 132 + d] = h[(b * 69 + r) * 128 + d];
  }
  for (int idx = tid; idx < 512; idx += 256)
    W4ld[(idx >> 7) * 132 + (idx & 127)] = W4[idx];
  for (int idx = tid; idx < NN; idx += 256)
    adjld[(idx / 69) * 70 + (idx % 69)] = (signed char)adj[b * NN + idx];
  __syncthreads();
  for (int t = tid; t < 630; t += 256) {  // 35*36/2 upper-tri 2x2 tiles
    int a = (int)((sqrtf(8.0f * (float)t + 1.0f) - 1.0f) * 0.5f);
    while ((a + 1) * (a + 2) / 2 <= t) ++a;
    while (a * (a + 1) / 2 > t) --a;
    const int ti = t - a * (a + 1) / 2;  // ti <= tj
    const int tj = a;
    const int i0 = ti * 2, i1 = min(i0 + 1, 68);
    const int j0 = tj * 2, j1 = min(j0 + 1, 68);
    float acc[4][4];  // [pair 00,01,10,11][k]
    #pragma unroll
    for (int p = 0; p < 4; ++p)
      #pragma unroll
      for (int k = 0; k < 4; ++k) acc[p][k] = 0.0f;
    const float* pi0 = hld + i0 * 132;
    const float* pi1 = hld + i1 * 132;
    const float* pj0 = hld + j0 * 132;
    const float* pj1 = hld + j1 * 132;
    #pragma unroll 4
    for (int d0 = 0; d0 < 128; d0 += 4) {
      float4 x0 = *(const float4*)(pi0 + d0);
      float4 x1 = *(const float4*)(pi1 + d0);
      float4 y0 = *(const float4*)(pj0 + d0);
      float4 y1 = *(const float4*)(pj1 + d0);
      float4 w0 = *(const float4*)(W4ld + 0 * 132 + d0);
      float4 w1 = *(const float4*)(W4ld + 1 * 132 + d0);
      float4 w2 = *(const float4*)(W4ld + 2 * 132 + d0);
      float4 w3 = *(const float4*)(W4ld + 3 * 132 + d0);
      float fx0[4] = {x0.x, x0.y, x0.z, x0.w};
      float fx1[4] = {x1.x, x1.y, x1.z, x1.w};
      float fy0[4] = {y0.x, y0.y, y0.z, y0.w};
      float fy1[4] = {y1.x, y1.y, y1.z, y1.w};
      float wk[4][4] = {{w0.x, w0.y, w0.z, w0.w},
                        {w1.x, w1.y, w1.z, w1.w},
                        {w2.x, w2.y, w2.z, w2.w},
                        {w3.x, w3.y, w3.z, w3.w}};
      #pragma unroll
      for (int dd = 0; dd < 4; ++dd) {
        float m00 = fx0[dd] * fy0[dd];
        float m01 = fx0[dd] * fy1[dd];
        float m10 = fx1[dd] * fy0[dd];
        float m11 = fx1[dd] * fy1[dd];
        #pragma unroll
        for (int k = 0; k < 4; ++k) {
          acc[0][k] = fmaf(m00, wk[k][dd], acc[0][k]);
          acc[1][k] = fmaf(m01, wk[k][dd], acc[1][k]);
          acc[2][k] = fmaf(m10, wk[k][dd], acc[2][k]);
          acc[3][k] = fmaf(m11, wk[k][dd], acc[3][k]);
        }
      }
    }
    const int ii[2] = {i0, i1}, jjx[2] = {j0, j1};
    #pragma unroll
    for (int pi_ = 0; pi_ < 2; ++pi_)
      #pragma unroll
      for (int pj_ = 0; pj_ < 2; ++pj_) {
        const int i = ii[pi_], j = jjx[pj_];
        if (i <= j) {  // lower-tri pair of a diagonal tile is the mirror of (0,1)
          const int p = pi_ * 2 + pj_;
          const int aij = adjld[i * 70 + j];
          const int aji = adjld[j * 70 + i];
          float sA = (aij <= 1) ? acc[p][0] : (aij == 2) ? acc[p][1]
                     : (aij == 3) ? acc[p][2] : acc[p][3];
          sA = (sA >= 0.0f) ? sA : 0.2f * sA;
          if (aij < 1) sA = NEGV;
          dst[b * NN + i * 69 + j] = sA;
          float sB = (aji <= 1) ? acc[p][0] : (aji == 2) ? acc[p][1]
                     : (aji == 3) ? acc[p][2] : acc[p][3];
          sB = (sB >= 0.0f) ? sB : 0.2f * sB;
          if (aji < 1) sB = NEGV;
          dst[b * NN + j * 69 + i] = sB;
        }
      }
  }
}

// ---------------- K4: entmax, 16-lanes-per-row (wave = 4 rows), native v_exp/v_log.
__device__ __forceinline__ float pcomp(float xs, float tau, float q) {
  float v = fmaxf(xs - tau, 0.0f);
  return fexp2(q * flog2(v));  // v=0 -> log=-inf -> exp2(-inf)=0
}

__device__ __forceinline__ float gsum16(float s) {
  #pragma unroll
  for (int d = 1; d < 16; d <<= 1) s += __shfl_xor(s, d, 16);
  return s;
}

__device__ __forceinline__ float bisect34w(const float (&x)[5], float am1, float q) {
  float mx = fmaxf(fmaxf(fmaxf(x[0], x[1]), fmaxf(x[2], x[3])), x[4]);
  #pragma unroll
  for (int d = 1; d < 16; d <<= 1) mx = fmaxf(mx, __shfl_xor(mx, d, 16));
  float tau_lo = mx - 1.0f;
  float tau_hi = mx - fexp2(am1 * flog2(1.0f / 69.0f));  // (1/d)^am1
  float dm = tau_hi - tau_lo;
  float tm = tau_lo;
  #pragma unroll 1
  for (int it = 0; it < 34; ++it) {
    dm *= 0.5f;
    tm = tau_lo + dm;
    float s = pcomp(x[0], tm, q) + pcomp(x[1], tm, q) + pcomp(x[2], tm, q) +
              pcomp(x[3], tm, q) + pcomp(x[4], tm, q);
    s = gsum16(s);
    if (s >= 1.0f) tau_lo = tm;  // butterfly sum is lane-uniform (commutative adds)
  }
  return tm;  // reference uses the last midpoint tau_m for p
}

__global__ __launch_bounds__(256) void k4_entmax(
    const float* __restrict__ alpha, int o,
    float* __restrict__ scA, const float* __restrict__ scB) {
  const int tid = threadIdx.x;
  const int wave = tid >> 6, lane = tid & 63;
  const int grp = lane >> 4, l16 = lane & 15;
  const int row = blockIdx.x * 16 + wave * 4 + grp;  // 0..70655 (4416 blocks)
  const int b = row / 69;
  const float am1A = alpha[o * 1024 + b];
  const float am1B = alpha[2048 + b];
  float* rowA = scA + 69u * (uint)row;
  const float* rowB = scB + 69u * (uint)row;
  // ---- side A
  const float qA = 1.0f / am1A;
  float x[5], pa[5];
  #pragma unroll
  for (int s = 0; s < 5; ++s) {
    int j = s * 16 + l16;
    x[s] = (j < 69) ? rowA[j] * am1A : -1.0e30f;  // pad -> v=0 -> p=0
  }
  const float tA = bisect34w(x, am1A, qA);
  float sA = 0.0f;
  #pragma unroll
  for (int s = 0; s < 5; ++s) { pa[s] = pcomp(x[s], tA, qA); sA += pa[s]; }
  sA = gsum16(sA);
  const float rsA = 1.0f / sA;
  // ---- side B (reuse x registers)
  const float qB = 1.0f / am1B;
  #pragma unroll
  for (int s = 0; s < 5; ++s) {
    int j = s * 16 + l16;
    x[s] = (j < 69) ? rowB[j] * am1B : -1.0e30f;
  }
  const float tB = bisect34w(x, am1B, qB);
  float sB = 0.0f;
  #pragma unroll
  for (int s = 0; s < 5; ++s) { x[s] = pcomp(x[s], tB, qB); sB += x[s]; }
  sB = gsum16(sB);
  const float rsB = 1.0f / sB;
  // ---- combine: w = (pA/sA)*(pB/sB) / (sum + 1e-7)
  float ws = 0.0f;
  #pragma unroll
  for (int s = 0; s < 5; ++s) { x[s] = (pa[s] * rsA) * (x[s] * rsB); ws += x[s]; }
  ws = gsum16(ws);
  const float rden = 1.0f / (ws + 1e-7f);
  #pragma unroll
  for (int s = 0; s < 5; ++s) {
    int j = s * 16 + l16;
    if (j < 69) rowA[j] = x[s] * rden;
  }
}

// ---------------- K5: out = w @ h (w f32 row-major, h f32, out f32)
__global__ __launch_bounds__(256) void k5_out(
    const float* __restrict__ h, const float* __restrict__ wsrc,
    float* __restrict__ outp) {
  const int b = blockIdx.x, tid = threadIdx.x;
  __shared__ float hld[69 * 132];  // 36,432 B
  __shared__ float wld[69 * 70];   // 19,320 B
  for (int idx = tid; idx < 69 * 128; idx += 256) {
    int r = idx >> 7, d = idx & 127;
    hld[r * 132 + d] = h[(b * 69 + r) * 128 + d];
  }
  for (int idx = tid; idx < NN; idx += 256) {
    int i = idx / 69, j = idx - i * 69;
    wld[i * 70 + j] = wsrc[b * NN + idx];
  }
  __syncthreads();
  for (int s = tid; s < 69 * 32; s += 256) {
    int i = s >> 5, dq = s & 31, d0 = dq << 2;
    float acc0 = 0, acc1 = 0, acc2 = 0, acc3 = 0;
    const float* wrow = wld + i * 70;
    const float* hcol = hld + d0;
    for (int j = 0; j < 69; ++j) {
      float wv = wrow[j];
      float4 hv = *(const float4*)(hcol + j * 132);
      acc0 = fmaf(wv, hv.x, acc0);
      acc1 = fmaf(wv, hv.y, acc1);
      acc2 = fmaf(wv, hv.z, acc2);
      acc3 = fmaf(wv, hv.w, acc3);
    }
    float4 ov = make_float4(acc0, acc1, acc2, acc3);
    *(float4*)(outp + (b * 69 + i) * 128 + d0) = ov;
  }
}

extern "C" void kernel_launch(void* const* d_in, const int* in_sizes, int n_in,
                              void* d_out, int out_size, void* d_ws, size_t ws_size,
                              hipStream_t stream) {
  (void)in_sizes; (void)n_in; (void)out_size;
  // Sf32 36,175,872 | alpha 12,288 | scA 19,501,056 | scB 19,501,056 = 75,190,272 B
  if (ws_size < 75190272u) return;  // early-return signature: absmax == 7.08e-2
  const float* in1 = (const float*)d_in[0];
  const float* in2 = (const float*)d_in[1];
  const float* se  = (const float*)d_in[2];
  const int* adjS  = (const int*)d_in[3];
  const int* adjND = (const int*)d_in[4];
  const float* mask = (const float*)d_in[5];
  const int* iidx  = (const int*)d_in[6];
  const float* Wl  = (const float*)d_in[8];
  const float* bl  = (const float*)d_in[9];
  const float* w1p = (const float*)d_in[10];
  const float* b1p = (const float*)d_in[11];
  const float* w2p = (const float*)d_in[12];
  const float* b2p = (const float*)d_in[13];
  const float* wSp = (const float*)d_in[14];
  const float* bSp = (const float*)d_in[15];
  const float* A1  = (const float*)d_in[16];
  const float* S1  = (const float*)d_in[17];
  const float* A2  = (const float*)d_in[18];
  const float* S2  = (const float*)d_in[19];
  float* Sf    = (float*)d_ws;
  float* alpha = (float*)((char*)d_ws + 36175872);
  float* scA   = (float*)((char*)d_ws + 36188160);
  float* scB   = (float*)((char*)d_ws + 55689216);
  float* outp  = (float*)d_out;

  k1_transform<<<dim3(1024), dim3(256), 0, stream>>>(se, Wl, bl, Sf);
  k2_alpha<<<dim3(1024), dim3(128), 0, stream>>>(in1, in2, Sf, mask, iidx,
                                                 w1p, b1p, w2p, b2p, wSp, bSp, alpha);
  // out1
  k3_scores<<<dim3(1024, 2), dim3(256), 0, stream>>>(in1, A1, scA, Sf, S1, scB, adjS);
  k4_entmax<<<dim3(4416), dim3(256), 0, stream>>>(alpha, 0, scA, scB);
  k5_out<<<dim3(1024), dim3(256), 0, stream>>>(in1, scA, outp);
  // out2
  k3_scores<<<dim3(1024, 2), dim3(256), 0, stream>>>(in2, A2, scA, Sf, S2, scB, adjND);
  k4_entmax<<<dim3(4416), dim3(256), 0, stream>>>(alpha, 1, scA, scB);
  k5_out<<<dim3(1024), dim3(256), 0, stream>>>(in2, scA, outp + SZ_S);
}

// Round 9
// 458.430 us; speedup vs baseline: 2.6617x; 1.3078x over previous
//
#include <hip/hip_runtime.h>

typedef unsigned int uint;
typedef unsigned short ushort;
typedef __attribute__((ext_vector_type(8))) short bf16x8;
typedef __attribute__((ext_vector_type(4))) float f32x4;

#define NN 4761            // 69*69
#define SZ_S 9043968       // 1024*69*128
#define NEGV -9000000.0f

// Native single-instruction transcendentals (base-2). v_log_f32(0) = -inf,
// v_exp_f32(-inf) = 0 -> masked elements produce p = 0 exactly.
__device__ __forceinline__ float fexp2(float x) {
  float r; asm("v_exp_f32 %0, %1" : "=v"(r) : "v"(x)); return r;
}
__device__ __forceinline__ float flog2(float x) {
  float r; asm("v_log_f32 %0, %1" : "=v"(r) : "v"(x)); return r;
}
// Packed f32->2xbf16 (RNE). Pack-order convention cancels: H and W4 are staged
// through the SAME instruction and unpacked with the SAME lo/hi helpers, and a
// within-lane K-permutation applied to BOTH mfma operands leaves the dot invariant.
__device__ __forceinline__ uint cvtpk(float lo, float hi) {
  uint r; asm("v_cvt_pk_bf16_f32 %0, %1, %2" : "=v"(r) : "v"(lo), "v"(hi)); return r;
}
__device__ __forceinline__ float b2f_lo(uint u) { return __uint_as_float(u << 16); }
__device__ __forceinline__ float b2f_hi(uint u) { return __uint_as_float(u & 0xFFFF0000u); }

// ---------------- K1: S = structure_embed @ W_lin^T + b_lin (all f32)
__global__ __launch_bounds__(256) void k1_transform(
    const float* __restrict__ se, const float* __restrict__ Wl,
    const float* __restrict__ bl, float* __restrict__ S) {
  __shared__ float seld[69 * 128];  // 35,328 B
  const int tid = threadIdx.x, b = blockIdx.x;
  const int rr = tid >> 7, i = tid & 127;
  float w[128];
  #pragma unroll
  for (int d0 = 0; d0 < 128; d0 += 4) {
    float4 v = *(const float4*)(Wl + i * 128 + d0);
    w[d0] = v.x; w[d0 + 1] = v.y; w[d0 + 2] = v.z; w[d0 + 3] = v.w;
  }
  for (int idx = tid; idx < 69 * 128; idx += 256) seld[idx] = se[b * 69 * 128 + idx];
  __syncthreads();
  const float bias = bl[i];
  for (int k = 0; k < 35; ++k) {
    int r = 2 * k + rr;
    if (r < 69) {
      float acc = bias;
      #pragma unroll
      for (int d0 = 0; d0 < 128; d0 += 4) {
        float4 sv = *(const float4*)(seld + r * 128 + d0);
        acc = fmaf(sv.x, w[d0], acc);
        acc = fmaf(sv.y, w[d0 + 1], acc);
        acc = fmaf(sv.z, w[d0 + 2], acc);
        acc = fmaf(sv.w, w[d0 + 3], acc);
      }
      S[(b * 69 + r) * 128 + i] = acc;
    }
  }
}

// ---------------- K2: alphas (stores am1 = alpha-1): [0..1023]=sem1, [1024..]=sem2, [2048..]=str
__global__ __launch_bounds__(128) void k2_alpha(
    const float* __restrict__ in1, const float* __restrict__ in2,
    const float* __restrict__ S, const float* __restrict__ mask,
    const int* __restrict__ iidx,
    const float* __restrict__ w1p, const float* __restrict__ b1p,
    const float* __restrict__ w2p, const float* __restrict__ b2p,
    const float* __restrict__ wSp, const float* __restrict__ bSp,
    float* __restrict__ alpha) {
  __shared__ float red[3][2];
  const int b = blockIdx.x, d = threadIdx.x;
  const int last = iidx[b * 69 + 68];
  float a1 = 0, a2 = 0, aS = 0, am = 0;
  const float* p1 = in1 + b * 69 * 128 + d;
  const float* p2 = in2 + b * 69 * 128 + d;
  const float* pS = S + b * 69 * 128 + d;
  const float* pm = mask + b * 69;
  for (int n = 0; n < 69; ++n) {
    float m = pm[n];
    a1 += p1[n * 128] * m;
    a2 += p2[n * 128] * m;
    aS += pS[n * 128] * m;
    am += m;
  }
  float z1 = (a1 / am + p1[last * 128]) * w1p[d];
  float z2 = (a2 / am + p2[last * 128]) * w2p[d];
  float zS = (aS / am + pS[last * 128]) * wSp[d];
  for (int off = 32; off >= 1; off >>= 1) {
    z1 += __shfl_down(z1, off);
    z2 += __shfl_down(z2, off);
    zS += __shfl_down(zS, off);
  }
  if ((d & 63) == 0) { int wv = d >> 6; red[0][wv] = z1; red[1][wv] = z2; red[2][wv] = zS; }
  __syncthreads();
  if (d == 0) {
    float r1 = 1.0f / (1.0f + expf(-(red[0][0] + red[0][1] + b1p[0]))) + 1.0f;
    float r2 = 1.0f / (1.0f + expf(-(red[1][0] + red[1][1] + b2p[0]))) + 1.0f;
    float rS = 1.0f / (1.0f + expf(-(red[2][0] + red[2][1] + bSp[0]))) + 1.0f;
    if (r1 == 1.0f) r1 = 1.0001f;
    if (r2 == 1.0f) r2 = 1.0001f;
    if (rS == 1.0f) rS = 1.0001f;
    alpha[b] = r1 - 1.0f;
    alpha[1024 + b] = r2 - 1.0f;
    alpha[2048 + b] = rS - 1.0f;
  }
}

// ---------------- K3 (MFMA): E_k = (H o w_k) @ H^T per (b, src); symmetric -> 15 upper
// 16x16 tiles of the padded 80x80 output. A-frag = bf16(h*w_k) scaled in-register;
// B-frag = bf16(h) from LDS. Epilogue: adj-select k, leaky, mask, write both orientations.
__global__ __launch_bounds__(256) void k3_scores(
    const float* __restrict__ hA, const float* __restrict__ W4A, float* __restrict__ dstA,
    const float* __restrict__ hB, const float* __restrict__ W4B, float* __restrict__ dstB,
    const int* __restrict__ adj) {
  const int b = blockIdx.x, tid = threadIdx.x;
  const float* h  = blockIdx.y ? hB : hA;
  const float* W4 = blockIdx.y ? W4B : W4A;
  float* dst      = blockIdx.y ? dstB : dstA;
  __shared__ ushort Hb[80 * 128];       // bf16, row pitch 256 B, XOR-swizzled chunks (20,480 B)
  __shared__ uint W4b[4 * 64];          // bf16-packed W4 (1,024 B)
  __shared__ signed char adjld[69 * 70];
  // ---- stage H (f32 -> bf16, swizzled: chunk c of row r lives at c^(r&7))
  for (int idx = tid; idx < 80 * 32; idx += 256) {
    int r = idx >> 5, q = idx & 31, d0 = q << 2;
    uint2 pk;
    if (r < 69) {
      float4 v = *(const float4*)(h + (b * 69 + r) * 128 + d0);
      pk.x = cvtpk(v.x, v.y);
      pk.y = cvtpk(v.z, v.w);
    } else { pk.x = 0u; pk.y = 0u; }  // zero pad rows 69..79
    *(uint2*)((char*)Hb + r * 256 + (((d0 >> 3) ^ (r & 7)) << 4) + ((d0 & 7) << 1)) = pk;
  }
  if (tid < 256) {  // all threads: 4k x 64 pairs
    int k = tid >> 6, dp = (tid & 63) << 1;
    W4b[k * 64 + (tid & 63)] = cvtpk(W4[k * 128 + dp], W4[k * 128 + dp + 1]);
  }
  for (int idx = tid; idx < NN; idx += 256)
    adjld[(idx / 69) * 70 + (idx % 69)] = (signed char)adj[b * NN + idx];
  __syncthreads();
  const int wv = tid >> 6, l = tid & 63;
  const int lc = l & 15, lq = l >> 4;
  #pragma unroll
  for (int s = 0; s < 4; ++s) {
    const int id = wv + 4 * s;            // wave w owns tiles w, w+4, w+8, w+12 (15 total)
    if (id < 15) {
      const int ti = (id < 5) ? 0 : (id < 9) ? 1 : (id < 12) ? 2 : (id < 14) ? 3 : 4;
      const int base = (ti == 0) ? 0 : (ti == 1) ? 5 : (ti == 2) ? 9 : (ti == 3) ? 12 : 14;
      const int tj = ti + (id - base);
      const int ra = ti * 16 + lc, rb = tj * 16 + lc;
      f32x4 acc0 = {0,0,0,0}, acc1 = {0,0,0,0}, acc2 = {0,0,0,0}, acc3 = {0,0,0,0};
      #pragma unroll
      for (int ks = 0; ks < 4; ++ks) {
        const int d0 = ks * 32 + lq * 8;  // multiple of 8 -> chunk-aligned
        uint4 araw = *(const uint4*)((const char*)Hb + ra * 256 + (((d0 >> 3) ^ (ra & 7)) << 4));
        uint4 braw = *(const uint4*)((const char*)Hb + rb * 256 + (((d0 >> 3) ^ (rb & 7)) << 4));
        float a0 = b2f_lo(araw.x), a1 = b2f_hi(araw.x);
        float a2 = b2f_lo(araw.y), a3 = b2f_hi(araw.y);
        float a4 = b2f_lo(araw.z), a5 = b2f_hi(araw.z);
        float a6 = b2f_lo(araw.w), a7 = b2f_hi(araw.w);
        bf16x8 bfrag = __builtin_bit_cast(bf16x8, braw);
        #pragma unroll
        for (int k = 0; k < 4; ++k) {
          uint4 wq = *(const uint4*)(W4b + k * 64 + (d0 >> 1));  // broadcast within 16 lanes
          uint4 ak;
          ak.x = cvtpk(a0 * b2f_lo(wq.x), a1 * b2f_hi(wq.x));
          ak.y = cvtpk(a2 * b2f_lo(wq.y), a3 * b2f_hi(wq.y));
          ak.z = cvtpk(a4 * b2f_lo(wq.z), a5 * b2f_hi(wq.z));
          ak.w = cvtpk(a6 * b2f_lo(wq.w), a7 * b2f_hi(wq.w));
          bf16x8 afrag = __builtin_bit_cast(bf16x8, ak);
          if (k == 0)      acc0 = __builtin_amdgcn_mfma_f32_16x16x32_bf16(afrag, bfrag, acc0, 0, 0, 0);
          else if (k == 1) acc1 = __builtin_amdgcn_mfma_f32_16x16x32_bf16(afrag, bfrag, acc1, 0, 0, 0);
          else if (k == 2) acc2 = __builtin_amdgcn_mfma_f32_16x16x32_bf16(afrag, bfrag, acc2, 0, 0, 0);
          else             acc3 = __builtin_amdgcn_mfma_f32_16x16x32_bf16(afrag, bfrag, acc3, 0, 0, 0);
        }
      }
      // ---- epilogue for this tile (C/D: col = l&15, row = (l>>4)*4 + reg [verified])
      const bool diag = (ti == tj);
      #pragma unroll
      for (int r = 0; r < 4; ++r) {
        const int ib = ti * 16 + lq * 4 + r;
        const int jb = tj * 16 + lc;
        if (ib < 69 && jb < 69 && (!diag || ib <= jb)) {
          const float e0 = acc0[r], e1 = acc1[r], e2 = acc2[r], e3 = acc3[r];
          const int aij = adjld[ib * 70 + jb];
          float sA = (aij <= 1) ? e0 : (aij == 2) ? e1 : (aij == 3) ? e2 : e3;
          sA = (sA >= 0.0f) ? sA : 0.2f * sA;
          if (aij < 1) sA = NEGV;
          dst[b * NN + ib * 69 + jb] = sA;
          const int aji = adjld[jb * 70 + ib];
          float sB = (aji <= 1) ? e0 : (aji == 2) ? e1 : (aji == 3) ? e2 : e3;
          sB = (sB >= 0.0f) ? sB : 0.2f * sB;
          if (aji < 1) sB = NEGV;
          dst[b * NN + jb * 69 + ib] = sB;
        }
      }
    }
  }
}

// ---------------- K4: entmax, 16-lanes-per-row (wave = 4 rows), native v_exp/v_log.
__device__ __forceinline__ float pcomp(float xs, float tau, float q) {
  float v = fmaxf(xs - tau, 0.0f);
  return fexp2(q * flog2(v));  // v=0 -> log=-inf -> exp2(-inf)=0
}

__device__ __forceinline__ float gsum16(float s) {
  #pragma unroll
  for (int d = 1; d < 16; d <<= 1) s += __shfl_xor(s, d, 16);
  return s;
}

__device__ __forceinline__ float bisect34w(const float (&x)[5], float am1, float q) {
  float mx = fmaxf(fmaxf(fmaxf(x[0], x[1]), fmaxf(x[2], x[3])), x[4]);
  #pragma unroll
  for (int d = 1; d < 16; d <<= 1) mx = fmaxf(mx, __shfl_xor(mx, d, 16));
  float tau_lo = mx - 1.0f;
  float tau_hi = mx - fexp2(am1 * flog2(1.0f / 69.0f));  // (1/d)^am1
  float dm = tau_hi - tau_lo;
  float tm = tau_lo;
  #pragma unroll 1
  for (int it = 0; it < 34; ++it) {
    dm *= 0.5f;
    tm = tau_lo + dm;
    float s = pcomp(x[0], tm, q) + pcomp(x[1], tm, q) + pcomp(x[2], tm, q) +
              pcomp(x[3], tm, q) + pcomp(x[4], tm, q);
    s = gsum16(s);
    if (s >= 1.0f) tau_lo = tm;  // butterfly sum is lane-uniform
  }
  return tm;  // reference uses the last midpoint tau_m for p
}

__global__ __launch_bounds__(256) void k4_entmax(
    const float* __restrict__ alpha, int o,
    float* __restrict__ scA, const float* __restrict__ scB) {
  const int tid = threadIdx.x;
  const int wave = tid >> 6, lane = tid & 63;
  const int grp = lane >> 4, l16 = lane & 15;
  const int row = blockIdx.x * 16 + wave * 4 + grp;  // 0..70655 (4416 blocks)
  const int b = row / 69;
  const float am1A = alpha[o * 1024 + b];
  const float am1B = alpha[2048 + b];
  float* rowA = scA + 69u * (uint)row;
  const float* rowB = scB + 69u * (uint)row;
  // ---- side A
  const float qA = 1.0f / am1A;
  float x[5], pa[5];
  #pragma unroll
  for (int s = 0; s < 5; ++s) {
    int j = s * 16 + l16;
    x[s] = (j < 69) ? rowA[j] * am1A : -1.0e30f;  // pad -> v=0 -> p=0
  }
  const float tA = bisect34w(x, am1A, qA);
  float sA = 0.0f;
  #pragma unroll
  for (int s = 0; s < 5; ++s) { pa[s] = pcomp(x[s], tA, qA); sA += pa[s]; }
  sA = gsum16(sA);
  const float rsA = 1.0f / sA;
  // ---- side B (reuse x registers)
  const float qB = 1.0f / am1B;
  #pragma unroll
  for (int s = 0; s < 5; ++s) {
    int j = s * 16 + l16;
    x[s] = (j < 69) ? rowB[j] * am1B : -1.0e30f;
  }
  const float tB = bisect34w(x, am1B, qB);
  float sB = 0.0f;
  #pragma unroll
  for (int s = 0; s < 5; ++s) { x[s] = pcomp(x[s], tB, qB); sB += x[s]; }
  sB = gsum16(sB);
  const float rsB = 1.0f / sB;
  // ---- combine: w = (pA/sA)*(pB/sB) / (sum + 1e-7)
  float ws = 0.0f;
  #pragma unroll
  for (int s = 0; s < 5; ++s) { x[s] = (pa[s] * rsA) * (x[s] * rsB); ws += x[s]; }
  ws = gsum16(ws);
  const float rden = 1.0f / (ws + 1e-7f);
  #pragma unroll
  for (int s = 0; s < 5; ++s) {
    int j = s * 16 + l16;
    if (j < 69) rowA[j] = x[s] * rden;
  }
}

// ---------------- K5: out = w @ h (w f32 row-major, h f32, out f32)
__global__ __launch_bounds__(256) void k5_out(
    const float* __restrict__ h, const float* __restrict__ wsrc,
    float* __restrict__ outp) {
  const int b = blockIdx.x, tid = threadIdx.x;
  __shared__ float hld[69 * 132];  // 36,432 B
  __shared__ float wld[69 * 70];   // 19,320 B
  for (int idx = tid; idx < 69 * 128; idx += 256) {
    int r = idx >> 7, d = idx & 127;
    hld[r * 132 + d] = h[(b * 69 + r) * 128 + d];
  }
  for (int idx = tid; idx < NN; idx += 256) {
    int i = idx / 69, j = idx - i * 69;
    wld[i * 70 + j] = wsrc[b * NN + idx];
  }
  __syncthreads();
  for (int s = tid; s < 69 * 32; s += 256) {
    int i = s >> 5, dq = s & 31, d0 = dq << 2;
    float acc0 = 0, acc1 = 0, acc2 = 0, acc3 = 0;
    const float* wrow = wld + i * 70;
    const float* hcol = hld + d0;
    for (int j = 0; j < 69; ++j) {
      float wv = wrow[j];
      float4 hv = *(const float4*)(hcol + j * 132);
      acc0 = fmaf(wv, hv.x, acc0);
      acc1 = fmaf(wv, hv.y, acc1);
      acc2 = fmaf(wv, hv.z, acc2);
      acc3 = fmaf(wv, hv.w, acc3);
    }
    float4 ov = make_float4(acc0, acc1, acc2, acc3);
    *(float4*)(outp + (b * 69 + i) * 128 + d0) = ov;
  }
}

extern "C" void kernel_launch(void* const* d_in, const int* in_sizes, int n_in,
                              void* d_out, int out_size, void* d_ws, size_t ws_size,
                              hipStream_t stream) {
  (void)in_sizes; (void)n_in; (void)out_size;
  // Sf32 36,175,872 | alpha 12,288 | scA 19,501,056 | scB 19,501,056 = 75,190,272 B
  if (ws_size < 75190272u) return;  // early-return signature: absmax == 7.08e-2
  const float* in1 = (const float*)d_in[0];
  const float* in2 = (const float*)d_in[1];
  const float* se  = (const float*)d_in[2];
  const int* adjS  = (const int*)d_in[3];
  const int* adjND = (const int*)d_in[4];
  const float* mask = (const float*)d_in[5];
  const int* iidx  = (const int*)d_in[6];
  const float* Wl  = (const float*)d_in[8];
  const float* bl  = (const float*)d_in[9];
  const float* w1p = (const float*)d_in[10];
  const float* b1p = (const float*)d_in[11];
  const float* w2p = (const float*)d_in[12];
  const float* b2p = (const float*)d_in[13];
  const float* wSp = (const float*)d_in[14];
  const float* bSp = (const float*)d_in[15];
  const float* A1  = (const float*)d_in[16];
  const float* S1  = (const float*)d_in[17];
  const float* A2  = (const float*)d_in[18];
  const float* S2  = (const float*)d_in[19];
  float* Sf    = (float*)d_ws;
  float* alpha = (float*)((char*)d_ws + 36175872);
  float* scA   = (float*)((char*)d_ws + 36188160);
  float* scB   = (float*)((char*)d_ws + 55689216);
  float* outp  = (float*)d_out;

  k1_transform<<<dim3(1024), dim3(256), 0, stream>>>(se, Wl, bl, Sf);
  k2_alpha<<<dim3(1024), dim3(128), 0, stream>>>(in1, in2, Sf, mask, iidx,
                                                 w1p, b1p, w2p, b2p, wSp, bSp, alpha);
  // out1
  k3_scores<<<dim3(1024, 2), dim3(256), 0, stream>>>(in1, A1, scA, Sf, S1, scB, adjS);
  k4_entmax<<<dim3(4416), dim3(256), 0, stream>>>(alpha, 0, scA, scB);
  k5_out<<<dim3(1024), dim3(256), 0, stream>>>(in1, scA, outp);
  // out2
  k3_scores<<<dim3(1024, 2), dim3(256), 0, stream>>>(in2, A2, scA, Sf, S2, scB, adjND);
  k4_entmax<<<dim3(4416), dim3(256), 0, stream>>>(alpha, 1, scA, scB);
  k5_out<<<dim3(1024), dim3(256), 0, stream>>>(in2, scA, outp + SZ_S);
}

// Round 11
// 437.861 us; speedup vs baseline: 2.7868x; 1.0470x over previous
//
#include <hip/hip_runtime.h>

typedef unsigned int uint;
typedef unsigned short ushort;
typedef __attribute__((ext_vector_type(8))) short bf16x8;
typedef __attribute__((ext_vector_type(4))) float f32x4;

#define NN 4761            // 69*69
#define SZ_S 9043968       // 1024*69*128
#define NEGV -9000000.0f

// Native single-instruction transcendentals (base-2). v_log_f32(0) = -inf,
// v_exp_f32(-inf) = 0 -> masked elements produce p = 0 exactly.
__device__ __forceinline__ float fexp2(float x) {
  float r; asm("v_exp_f32 %0, %1" : "=v"(r) : "v"(x)); return r;
}
__device__ __forceinline__ float flog2(float x) {
  float r; asm("v_log_f32 %0, %1" : "=v"(r) : "v"(x)); return r;
}
// Packed f32->2xbf16 (RNE). Pack-order convention cancels between A and B operands.
__device__ __forceinline__ uint cvtpk(float lo, float hi) {
  uint r; asm("v_cvt_pk_bf16_f32 %0, %1, %2" : "=v"(r) : "v"(lo), "v"(hi)); return r;
}
__device__ __forceinline__ float b2f_lo(uint u) { return __uint_as_float(u << 16); }
__device__ __forceinline__ float b2f_hi(uint u) { return __uint_as_float(u & 0xFFFF0000u); }

// 16-lane group reductions via xor-butterfly shuffles. NOTE (r10 post-mortem): the
// butterfly is bitwise lane-uniform (lanes i and i^d add the same two floats each
// step; fp add is commutative) so the s>=1 bisection branch cannot diverge within a
// group. DPP row_ror reductions are NOT lane-uniform and caused a replay-unstable
// failure in r10 -- do not reintroduce without disasm-level evidence.
__device__ __forceinline__ float gsum16(float s) {
  #pragma unroll
  for (int d = 1; d < 16; d <<= 1) s += __shfl_xor(s, d, 16);
  return s;
}
__device__ __forceinline__ float gmax16(float m) {
  #pragma unroll
  for (int d = 1; d < 16; d <<= 1) m = fmaxf(m, __shfl_xor(m, d, 16));
  return m;
}

// ---------------- K1: S = structure_embed @ W_lin^T + b_lin (all f32)
__global__ __launch_bounds__(256) void k1_transform(
    const float* __restrict__ se, const float* __restrict__ Wl,
    const float* __restrict__ bl, float* __restrict__ S) {
  __shared__ float seld[69 * 128];  // 35,328 B
  const int tid = threadIdx.x, b = blockIdx.x;
  const int rr = tid >> 7, i = tid & 127;
  float w[128];
  #pragma unroll
  for (int d0 = 0; d0 < 128; d0 += 4) {
    float4 v = *(const float4*)(Wl + i * 128 + d0);
    w[d0] = v.x; w[d0 + 1] = v.y; w[d0 + 2] = v.z; w[d0 + 3] = v.w;
  }
  for (int idx = tid; idx < 69 * 128; idx += 256) seld[idx] = se[b * 69 * 128 + idx];
  __syncthreads();
  const float bias = bl[i];
  for (int k = 0; k < 35; ++k) {
    int r = 2 * k + rr;
    if (r < 69) {
      float acc = bias;
      #pragma unroll
      for (int d0 = 0; d0 < 128; d0 += 4) {
        float4 sv = *(const float4*)(seld + r * 128 + d0);
        acc = fmaf(sv.x, w[d0], acc);
        acc = fmaf(sv.y, w[d0 + 1], acc);
        acc = fmaf(sv.z, w[d0 + 2], acc);
        acc = fmaf(sv.w, w[d0 + 3], acc);
      }
      S[(b * 69 + r) * 128 + i] = acc;
    }
  }
}

// ---------------- K2: alphas (stores am1 = alpha-1): [0..1023]=sem1, [1024..]=sem2, [2048..]=str
__global__ __launch_bounds__(128) void k2_alpha(
    const float* __restrict__ in1, const float* __restrict__ in2,
    const float* __restrict__ S, const float* __restrict__ mask,
    const int* __restrict__ iidx,
    const float* __restrict__ w1p, const float* __restrict__ b1p,
    const float* __restrict__ w2p, const float* __restrict__ b2p,
    const float* __restrict__ wSp, const float* __restrict__ bSp,
    float* __restrict__ alpha) {
  __shared__ float red[3][2];
  const int b = blockIdx.x, d = threadIdx.x;
  const int last = iidx[b * 69 + 68];
  float a1 = 0, a2 = 0, aS = 0, am = 0;
  const float* p1 = in1 + b * 69 * 128 + d;
  const float* p2 = in2 + b * 69 * 128 + d;
  const float* pS = S + b * 69 * 128 + d;
  const float* pm = mask + b * 69;
  for (int n = 0; n < 69; ++n) {
    float m = pm[n];
    a1 += p1[n * 128] * m;
    a2 += p2[n * 128] * m;
    aS += pS[n * 128] * m;
    am += m;
  }
  float z1 = (a1 / am + p1[last * 128]) * w1p[d];
  float z2 = (a2 / am + p2[last * 128]) * w2p[d];
  float zS = (aS / am + pS[last * 128]) * wSp[d];
  for (int off = 32; off >= 1; off >>= 1) {
    z1 += __shfl_down(z1, off);
    z2 += __shfl_down(z2, off);
    zS += __shfl_down(zS, off);
  }
  if ((d & 63) == 0) { int wv = d >> 6; red[0][wv] = z1; red[1][wv] = z2; red[2][wv] = zS; }
  __syncthreads();
  if (d == 0) {
    float r1 = 1.0f / (1.0f + expf(-(red[0][0] + red[0][1] + b1p[0]))) + 1.0f;
    float r2 = 1.0f / (1.0f + expf(-(red[1][0] + red[1][1] + b2p[0]))) + 1.0f;
    float rS = 1.0f / (1.0f + expf(-(red[2][0] + red[2][1] + bSp[0]))) + 1.0f;
    if (r1 == 1.0f) r1 = 1.0001f;
    if (r2 == 1.0f) r2 = 1.0001f;
    if (rS == 1.0f) rS = 1.0001f;
    alpha[b] = r1 - 1.0f;
    alpha[1024 + b] = r2 - 1.0f;
    alpha[2048 + b] = rS - 1.0f;
  }
}

// ---------------- K3 (MFMA): E_k = (H o w_k) @ H^T per (b, src); symmetric -> 15 upper
// 16x16 tiles of the padded 80x80 output. A-frag = bf16(h*w_k) scaled in-register;
// B-frag = bf16(h) from LDS. Epilogue: adj-select k, leaky, mask, write both orientations.
__global__ __launch_bounds__(256) void k3_scores(
    const float* __restrict__ hA, const float* __restrict__ W4A, float* __restrict__ dstA,
    const float* __restrict__ hB, const float* __restrict__ W4B, float* __restrict__ dstB,
    const int* __restrict__ adj) {
  const int b = blockIdx.x, tid = threadIdx.x;
  const float* h  = blockIdx.y ? hB : hA;
  const float* W4 = blockIdx.y ? W4B : W4A;
  float* dst      = blockIdx.y ? dstB : dstA;
  __shared__ ushort Hb[80 * 128];       // bf16, row pitch 256 B, XOR-swizzled chunks (20,480 B)
  __shared__ uint W4b[4 * 64];          // bf16-packed W4 (1,024 B)
  __shared__ signed char adjld[69 * 70];
  // ---- stage H (f32 -> bf16, swizzled: chunk c of row r lives at c^(r&7))
  for (int idx = tid; idx < 80 * 32; idx += 256) {
    int r = idx >> 5, q = idx & 31, d0 = q << 2;
    uint2 pk;
    if (r < 69) {
      float4 v = *(const float4*)(h + (b * 69 + r) * 128 + d0);
      pk.x = cvtpk(v.x, v.y);
      pk.y = cvtpk(v.z, v.w);
    } else { pk.x = 0u; pk.y = 0u; }  // zero pad rows 69..79
    *(uint2*)((char*)Hb + r * 256 + (((d0 >> 3) ^ (r & 7)) << 4) + ((d0 & 7) << 1)) = pk;
  }
  if (tid < 256) {  // all threads: 4k x 64 pairs
    int k = tid >> 6, dp = (tid & 63) << 1;
    W4b[k * 64 + (tid & 63)] = cvtpk(W4[k * 128 + dp], W4[k * 128 + dp + 1]);
  }
  for (int idx = tid; idx < NN; idx += 256)
    adjld[(idx / 69) * 70 + (idx % 69)] = (signed char)adj[b * NN + idx];
  __syncthreads();
  const int wv = tid >> 6, l = tid & 63;
  const int lc = l & 15, lq = l >> 4;
  #pragma unroll
  for (int s = 0; s < 4; ++s) {
    const int id = wv + 4 * s;            // wave w owns tiles w, w+4, w+8, w+12 (15 total)
    if (id < 15) {
      const int ti = (id < 5) ? 0 : (id < 9) ? 1 : (id < 12) ? 2 : (id < 14) ? 3 : 4;
      const int base = (ti == 0) ? 0 : (ti == 1) ? 5 : (ti == 2) ? 9 : (ti == 3) ? 12 : 14;
      const int tj = ti + (id - base);
      const int ra = ti * 16 + lc, rb = tj * 16 + lc;
      f32x4 acc0 = {0,0,0,0}, acc1 = {0,0,0,0}, acc2 = {0,0,0,0}, acc3 = {0,0,0,0};
      #pragma unroll
      for (int ks = 0; ks < 4; ++ks) {
        const int d0 = ks * 32 + lq * 8;  // multiple of 8 -> chunk-aligned
        uint4 araw = *(const uint4*)((const char*)Hb + ra * 256 + (((d0 >> 3) ^ (ra & 7)) << 4));
        uint4 braw = *(const uint4*)((const char*)Hb + rb * 256 + (((d0 >> 3) ^ (rb & 7)) << 4));
        float a0 = b2f_lo(araw.x), a1 = b2f_hi(araw.x);
        float a2 = b2f_lo(araw.y), a3 = b2f_hi(araw.y);
        float a4 = b2f_lo(araw.z), a5 = b2f_hi(araw.z);
        float a6 = b2f_lo(araw.w), a7 = b2f_hi(araw.w);
        bf16x8 bfrag = __builtin_bit_cast(bf16x8, braw);
        #pragma unroll
        for (int k = 0; k < 4; ++k) {
          uint4 wq = *(const uint4*)(W4b + k * 64 + (d0 >> 1));  // broadcast within 16 lanes
          uint4 ak;
          ak.x = cvtpk(a0 * b2f_lo(wq.x), a1 * b2f_hi(wq.x));
          ak.y = cvtpk(a2 * b2f_lo(wq.y), a3 * b2f_hi(wq.y));
          ak.z = cvtpk(a4 * b2f_lo(wq.z), a5 * b2f_hi(wq.z));
          ak.w = cvtpk(a6 * b2f_lo(wq.w), a7 * b2f_hi(wq.w));
          bf16x8 afrag = __builtin_bit_cast(bf16x8, ak);
          if (k == 0)      acc0 = __builtin_amdgcn_mfma_f32_16x16x32_bf16(afrag, bfrag, acc0, 0, 0, 0);
          else if (k == 1) acc1 = __builtin_amdgcn_mfma_f32_16x16x32_bf16(afrag, bfrag, acc1, 0, 0, 0);
          else if (k == 2) acc2 = __builtin_amdgcn_mfma_f32_16x16x32_bf16(afrag, bfrag, acc2, 0, 0, 0);
          else             acc3 = __builtin_amdgcn_mfma_f32_16x16x32_bf16(afrag, bfrag, acc3, 0, 0, 0);
        }
      }
      // ---- epilogue for this tile (C/D: col = l&15, row = (l>>4)*4 + reg [verified])
      const bool diag = (ti == tj);
      #pragma unroll
      for (int r = 0; r < 4; ++r) {
        const int ib = ti * 16 + lq * 4 + r;
        const int jb = tj * 16 + lc;
        if (ib < 69 && jb < 69 && (!diag || ib <= jb)) {
          const float e0 = acc0[r], e1 = acc1[r], e2 = acc2[r], e3 = acc3[r];
          const int aij = adjld[ib * 70 + jb];
          float sA = (aij <= 1) ? e0 : (aij == 2) ? e1 : (aij == 3) ? e2 : e3;
          sA = (sA >= 0.0f) ? sA : 0.2f * sA;
          if (aij < 1) sA = NEGV;
          dst[b * NN + ib * 69 + jb] = sA;
          const int aji = adjld[jb * 70 + ib];
          float sB = (aji <= 1) ? e0 : (aji == 2) ? e1 : (aji == 3) ? e2 : e3;
          sB = (sB >= 0.0f) ? sB : 0.2f * sB;
          if (aji < 1) sB = NEGV;
          dst[b * NN + jb * 69 + ib] = sB;
        }
      }
    }
  }
}

// ---------------- K4: entmax, 16-lanes-per-row (wave = 4 rows), native v_exp/v_log,
// xor-butterfly reductions (lane-uniform). 30 iters: |tau err| <= dm0*2^-30 ~ 8e-10.
__device__ __forceinline__ float pcomp(float xs, float tau, float q) {
  float v = fmaxf(xs - tau, 0.0f);
  return fexp2(q * flog2(v));  // v=0 -> log=-inf -> exp2(-inf)=0
}

__device__ __forceinline__ float bisect30w(const float (&x)[5], float am1, float q) {
  float mx = gmax16(fmaxf(fmaxf(fmaxf(x[0], x[1]), fmaxf(x[2], x[3])), x[4]));
  float tau_lo = mx - 1.0f;
  float tau_hi = mx - fexp2(am1 * flog2(1.0f / 69.0f));  // (1/d)^am1
  float dm = tau_hi - tau_lo;
  float tm = tau_lo;
  #pragma unroll 1
  for (int it = 0; it < 30; ++it) {
    dm *= 0.5f;
    tm = tau_lo + dm;
    float s = pcomp(x[0], tm, q) + pcomp(x[1], tm, q) + pcomp(x[2], tm, q) +
              pcomp(x[3], tm, q) + pcomp(x[4], tm, q);
    s = gsum16(s);
    if (s >= 1.0f) tau_lo = tm;  // butterfly sum is bitwise lane-uniform
  }
  return tm;  // reference uses the last midpoint tau_m for p
}

__global__ __launch_bounds__(256) void k4_entmax(
    const float* __restrict__ alpha, int o,
    float* __restrict__ scA, const float* __restrict__ scB) {
  const int tid = threadIdx.x;
  const int wave = tid >> 6, lane = tid & 63;
  const int grp = lane >> 4, l16 = lane & 15;
  const int row = blockIdx.x * 16 + wave * 4 + grp;  // 0..70655 (4416 blocks)
  const int b = row / 69;
  const float am1A = alpha[o * 1024 + b];
  const float am1B = alpha[2048 + b];
  float* rowA = scA + 69u * (uint)row;
  const float* rowB = scB + 69u * (uint)row;
  // ---- side A
  const float qA = 1.0f / am1A;
  float x[5], pa[5];
  #pragma unroll
  for (int s = 0; s < 5; ++s) {
    int j = s * 16 + l16;
    x[s] = (j < 69) ? rowA[j] * am1A : -1.0e30f;  // pad -> v=0 -> p=0
  }
  const float tA = bisect30w(x, am1A, qA);
  float sA = 0.0f;
  #pragma unroll
  for (int s = 0; s < 5; ++s) { pa[s] = pcomp(x[s], tA, qA); sA += pa[s]; }
  sA = gsum16(sA);
  const float rsA = 1.0f / sA;
  // ---- side B (reuse x registers)
  const float qB = 1.0f / am1B;
  #pragma unroll
  for (int s = 0; s < 5; ++s) {
    int j = s * 16 + l16;
    x[s] = (j < 69) ? rowB[j] * am1B : -1.0e30f;
  }
  const float tB = bisect30w(x, am1B, qB);
  float sB = 0.0f;
  #pragma unroll
  for (int s = 0; s < 5; ++s) { x[s] = pcomp(x[s], tB, qB); sB += x[s]; }
  sB = gsum16(sB);
  const float rsB = 1.0f / sB;
  // ---- combine: w = (pA/sA)*(pB/sB) / (sum + 1e-7)
  float ws = 0.0f;
  #pragma unroll
  for (int s = 0; s < 5; ++s) { x[s] = (pa[s] * rsA) * (x[s] * rsB); ws += x[s]; }
  ws = gsum16(ws);
  const float rden = 1.0f / (ws + 1e-7f);
  #pragma unroll
  for (int s = 0; s < 5; ++s) {
    int j = s * 16 + l16;
    if (j < 69) rowA[j] = x[s] * rden;
  }
}

// ---------------- K5: out = w @ h (w f32 row-major, h f32, out f32)
__global__ __launch_bounds__(256) void k5_out(
    const float* __restrict__ h, const float* __restrict__ wsrc,
    float* __restrict__ outp) {
  const int b = blockIdx.x, tid = threadIdx.x;
  __shared__ float hld[69 * 132];  // 36,432 B
  __shared__ float wld[69 * 70];   // 19,320 B
  for (int idx = tid; idx < 69 * 128; idx += 256) {
    int r = idx >> 7, d = idx & 127;
    hld[r * 132 + d] = h[(b * 69 + r) * 128 + d];
  }
  for (int idx = tid; idx < NN; idx += 256) {
    int i = idx / 69, j = idx - i * 69;
    wld[i * 70 + j] = wsrc[b * NN + idx];
  }
  __syncthreads();
  for (int s = tid; s < 69 * 32; s += 256) {
    int i = s >> 5, dq = s & 31, d0 = dq << 2;
    float acc0 = 0, acc1 = 0, acc2 = 0, acc3 = 0;
    const float* wrow = wld + i * 70;
    const float* hcol = hld + d0;
    for (int j = 0; j < 69; ++j) {
      float wv = wrow[j];
      float4 hv = *(const float4*)(hcol + j * 132);
      acc0 = fmaf(wv, hv.x, acc0);
      acc1 = fmaf(wv, hv.y, acc1);
      acc2 = fmaf(wv, hv.z, acc2);
      acc3 = fmaf(wv, hv.w, acc3);
    }
    float4 ov = make_float4(acc0, acc1, acc2, acc3);
    *(float4*)(outp + (b * 69 + i) * 128 + d0) = ov;
  }
}

extern "C" void kernel_launch(void* const* d_in, const int* in_sizes, int n_in,
                              void* d_out, int out_size, void* d_ws, size_t ws_size,
                              hipStream_t stream) {
  (void)in_sizes; (void)n_in; (void)out_size;
  // Sf32 36,175,872 | alpha 12,288 | scA 19,501,056 | scB 19,501,056 = 75,190,272 B
  if (ws_size < 75190272u) return;  // early-return signature: absmax == 7.08e-2
  const float* in1 = (const float*)d_in[0];
  const float* in2 = (const float*)d_in[1];
  const float* se  = (const float*)d_in[2];
  const int* adjS  = (const int*)d_in[3];
  const int* adjND = (const int*)d_in[4];
  const float* mask = (const float*)d_in[5];
  const int* iidx  = (const int*)d_in[6];
  const float* Wl  = (const float*)d_in[8];
  const float* bl  = (const float*)d_in[9];
  const float* w1p = (const float*)d_in[10];
  const float* b1p = (const float*)d_in[11];
  const float* w2p = (const float*)d_in[12];
  const float* b2p = (const float*)d_in[13];
  const float* wSp = (const float*)d_in[14];
  const float* bSp = (const float*)d_in[15];
  const float* A1  = (const float*)d_in[16];
  const float* S1  = (const float*)d_in[17];
  const float* A2  = (const float*)d_in[18];
  const float* S2  = (const float*)d_in[19];
  float* Sf    = (float*)d_ws;
  float* alpha = (float*)((char*)d_ws + 36175872);
  float* scA   = (float*)((char*)d_ws + 36188160);
  float* scB   = (float*)((char*)d_ws + 55689216);
  float* outp  = (float*)d_out;

  k1_transform<<<dim3(1024), dim3(256), 0, stream>>>(se, Wl, bl, Sf);
  k2_alpha<<<dim3(1024), dim3(128), 0, stream>>>(in1, in2, Sf, mask, iidx,
                                                 w1p, b1p, w2p, b2p, wSp, bSp, alpha);
  // out1
  k3_scores<<<dim3(1024, 2), dim3(256), 0, stream>>>(in1, A1, scA, Sf, S1, scB, adjS);
  k4_entmax<<<dim3(4416), dim3(256), 0, stream>>>(alpha, 0, scA, scB);
  k5_out<<<dim3(1024), dim3(256), 0, stream>>>(in1, scA, outp);
  // out2
  k3_scores<<<dim3(1024, 2), dim3(256), 0, stream>>>(in2, A2, scA, Sf, S2, scB, adjND);
  k4_entmax<<<dim3(4416), dim3(256), 0, stream>>>(alpha, 1, scA, scB);
  k5_out<<<dim3(1024), dim3(256), 0, stream>>>(in2, scA, outp + SZ_S);
}

// Round 12
// 387.513 us; speedup vs baseline: 3.1489x; 1.1299x over previous
//
#include <hip/hip_runtime.h>

typedef unsigned int uint;
typedef unsigned short ushort;
typedef __attribute__((ext_vector_type(8))) short bf16x8;
typedef __attribute__((ext_vector_type(4))) float f32x4;

#define NN 4761            // 69*69
#define SZ_S 9043968       // 1024*69*128
#define NEGV -9000000.0f

// Native single-instruction transcendentals (base-2). v_log_f32(0) = -inf,
// v_exp_f32(-inf) = 0 -> masked elements produce p = 0 exactly.
__device__ __forceinline__ float fexp2(float x) {
  float r; asm("v_exp_f32 %0, %1" : "=v"(r) : "v"(x)); return r;
}
__device__ __forceinline__ float flog2(float x) {
  float r; asm("v_log_f32 %0, %1" : "=v"(r) : "v"(x)); return r;
}
// Packed f32->2xbf16 (RNE). Pack-order convention cancels between A and B operands.
__device__ __forceinline__ uint cvtpk(float lo, float hi) {
  uint r; asm("v_cvt_pk_bf16_f32 %0, %1, %2" : "=v"(r) : "v"(lo), "v"(hi)); return r;
}
__device__ __forceinline__ float b2f_lo(uint u) { return __uint_as_float(u << 16); }
__device__ __forceinline__ float b2f_hi(uint u) { return __uint_as_float(u & 0xFFFF0000u); }

// 16-lane group reductions via xor-butterfly shuffles. NOTE (r10 post-mortem): the
// butterfly is bitwise lane-uniform (lanes i and i^d add the same two floats each
// step; fp add is commutative) so the s>=1 bisection branch cannot diverge within a
// group. DPP row_ror reductions are NOT lane-uniform and caused a replay-unstable
// failure in r10 -- do not reintroduce without disasm-level evidence.
__device__ __forceinline__ float gsum16(float s) {
  #pragma unroll
  for (int d = 1; d < 16; d <<= 1) s += __shfl_xor(s, d, 16);
  return s;
}
__device__ __forceinline__ float gmax16(float m) {
  #pragma unroll
  for (int d = 1; d < 16; d <<= 1) m = fmaxf(m, __shfl_xor(m, d, 16));
  return m;
}

// ---------------- K1: S = structure_embed @ W_lin^T + b_lin (all f32)
__global__ __launch_bounds__(256) void k1_transform(
    const float* __restrict__ se, const float* __restrict__ Wl,
    const float* __restrict__ bl, float* __restrict__ S) {
  __shared__ float seld[69 * 128];  // 35,328 B
  const int tid = threadIdx.x, b = blockIdx.x;
  const int rr = tid >> 7, i = tid & 127;
  float w[128];
  #pragma unroll
  for (int d0 = 0; d0 < 128; d0 += 4) {
    float4 v = *(const float4*)(Wl + i * 128 + d0);
    w[d0] = v.x; w[d0 + 1] = v.y; w[d0 + 2] = v.z; w[d0 + 3] = v.w;
  }
  for (int idx = tid; idx < 69 * 128; idx += 256) seld[idx] = se[b * 69 * 128 + idx];
  __syncthreads();
  const float bias = bl[i];
  for (int k = 0; k < 35; ++k) {
    int r = 2 * k + rr;
    if (r < 69) {
      float acc = bias;
      #pragma unroll
      for (int d0 = 0; d0 < 128; d0 += 4) {
        float4 sv = *(const float4*)(seld + r * 128 + d0);
        acc = fmaf(sv.x, w[d0], acc);
        acc = fmaf(sv.y, w[d0 + 1], acc);
        acc = fmaf(sv.z, w[d0 + 2], acc);
        acc = fmaf(sv.w, w[d0 + 3], acc);
      }
      S[(b * 69 + r) * 128 + i] = acc;
    }
  }
}

// ---------------- K2: alphas (stores am1 = alpha-1): [0..1023]=sem1, [1024..]=sem2, [2048..]=str
__global__ __launch_bounds__(128) void k2_alpha(
    const float* __restrict__ in1, const float* __restrict__ in2,
    const float* __restrict__ S, const float* __restrict__ mask,
    const int* __restrict__ iidx,
    const float* __restrict__ w1p, const float* __restrict__ b1p,
    const float* __restrict__ w2p, const float* __restrict__ b2p,
    const float* __restrict__ wSp, const float* __restrict__ bSp,
    float* __restrict__ alpha) {
  __shared__ float red[3][2];
  const int b = blockIdx.x, d = threadIdx.x;
  const int last = iidx[b * 69 + 68];
  float a1 = 0, a2 = 0, aS = 0, am = 0;
  const float* p1 = in1 + b * 69 * 128 + d;
  const float* p2 = in2 + b * 69 * 128 + d;
  const float* pS = S + b * 69 * 128 + d;
  const float* pm = mask + b * 69;
  for (int n = 0; n < 69; ++n) {
    float m = pm[n];
    a1 += p1[n * 128] * m;
    a2 += p2[n * 128] * m;
    aS += pS[n * 128] * m;
    am += m;
  }
  float z1 = (a1 / am + p1[last * 128]) * w1p[d];
  float z2 = (a2 / am + p2[last * 128]) * w2p[d];
  float zS = (aS / am + pS[last * 128]) * wSp[d];
  for (int off = 32; off >= 1; off >>= 1) {
    z1 += __shfl_down(z1, off);
    z2 += __shfl_down(z2, off);
    zS += __shfl_down(zS, off);
  }
  if ((d & 63) == 0) { int wv = d >> 6; red[0][wv] = z1; red[1][wv] = z2; red[2][wv] = zS; }
  __syncthreads();
  if (d == 0) {
    float r1 = 1.0f / (1.0f + expf(-(red[0][0] + red[0][1] + b1p[0]))) + 1.0f;
    float r2 = 1.0f / (1.0f + expf(-(red[1][0] + red[1][1] + b2p[0]))) + 1.0f;
    float rS = 1.0f / (1.0f + expf(-(red[2][0] + red[2][1] + bSp[0]))) + 1.0f;
    if (r1 == 1.0f) r1 = 1.0001f;
    if (r2 == 1.0f) r2 = 1.0001f;
    if (rS == 1.0f) rS = 1.0001f;
    alpha[b] = r1 - 1.0f;
    alpha[1024 + b] = r2 - 1.0f;
    alpha[2048 + b] = rS - 1.0f;
  }
}

// ---------------- K3 (MFMA): E_k = (H o w_k) @ H^T per (b, src); symmetric -> 15 upper
// 16x16 tiles of the padded 80x80 output. A-frag = bf16(h*w_k) scaled in-register;
// B-frag = bf16(h) from LDS. Epilogue: adj-select k, leaky, mask, write both orientations.
__global__ __launch_bounds__(256) void k3_scores(
    const float* __restrict__ hA, const float* __restrict__ W4A, float* __restrict__ dstA,
    const float* __restrict__ hB, const float* __restrict__ W4B, float* __restrict__ dstB,
    const int* __restrict__ adj) {
  const int b = blockIdx.x, tid = threadIdx.x;
  const float* h  = blockIdx.y ? hB : hA;
  const float* W4 = blockIdx.y ? W4B : W4A;
  float* dst      = blockIdx.y ? dstB : dstA;
  __shared__ ushort Hb[80 * 128];       // bf16, row pitch 256 B, XOR-swizzled chunks (20,480 B)
  __shared__ uint W4b[4 * 64];          // bf16-packed W4 (1,024 B)
  __shared__ signed char adjld[69 * 70];
  // ---- stage H (f32 -> bf16, swizzled: chunk c of row r lives at c^(r&7))
  for (int idx = tid; idx < 80 * 32; idx += 256) {
    int r = idx >> 5, q = idx & 31, d0 = q << 2;
    uint2 pk;
    if (r < 69) {
      float4 v = *(const float4*)(h + (b * 69 + r) * 128 + d0);
      pk.x = cvtpk(v.x, v.y);
      pk.y = cvtpk(v.z, v.w);
    } else { pk.x = 0u; pk.y = 0u; }  // zero pad rows 69..79
    *(uint2*)((char*)Hb + r * 256 + (((d0 >> 3) ^ (r & 7)) << 4) + ((d0 & 7) << 1)) = pk;
  }
  if (tid < 256) {  // all threads: 4k x 64 pairs
    int k = tid >> 6, dp = (tid & 63) << 1;
    W4b[k * 64 + (tid & 63)] = cvtpk(W4[k * 128 + dp], W4[k * 128 + dp + 1]);
  }
  for (int idx = tid; idx < NN; idx += 256)
    adjld[(idx / 69) * 70 + (idx % 69)] = (signed char)adj[b * NN + idx];
  __syncthreads();
  const int wv = tid >> 6, l = tid & 63;
  const int lc = l & 15, lq = l >> 4;
  #pragma unroll
  for (int s = 0; s < 4; ++s) {
    const int id = wv + 4 * s;            // wave w owns tiles w, w+4, w+8, w+12 (15 total)
    if (id < 15) {
      const int ti = (id < 5) ? 0 : (id < 9) ? 1 : (id < 12) ? 2 : (id < 14) ? 3 : 4;
      const int base = (ti == 0) ? 0 : (ti == 1) ? 5 : (ti == 2) ? 9 : (ti == 3) ? 12 : 14;
      const int tj = ti + (id - base);
      const int ra = ti * 16 + lc, rb = tj * 16 + lc;
      f32x4 acc0 = {0,0,0,0}, acc1 = {0,0,0,0}, acc2 = {0,0,0,0}, acc3 = {0,0,0,0};
      #pragma unroll
      for (int ks = 0; ks < 4; ++ks) {
        const int d0 = ks * 32 + lq * 8;  // multiple of 8 -> chunk-aligned
        uint4 araw = *(const uint4*)((const char*)Hb + ra * 256 + (((d0 >> 3) ^ (ra & 7)) << 4));
        uint4 braw = *(const uint4*)((const char*)Hb + rb * 256 + (((d0 >> 3) ^ (rb & 7)) << 4));
        float a0 = b2f_lo(araw.x), a1 = b2f_hi(araw.x);
        float a2 = b2f_lo(araw.y), a3 = b2f_hi(araw.y);
        float a4 = b2f_lo(araw.z), a5 = b2f_hi(araw.z);
        float a6 = b2f_lo(araw.w), a7 = b2f_hi(araw.w);
        bf16x8 bfrag = __builtin_bit_cast(bf16x8, braw);
        #pragma unroll
        for (int k = 0; k < 4; ++k) {
          uint4 wq = *(const uint4*)(W4b + k * 64 + (d0 >> 1));  // broadcast within 16 lanes
          uint4 ak;
          ak.x = cvtpk(a0 * b2f_lo(wq.x), a1 * b2f_hi(wq.x));
          ak.y = cvtpk(a2 * b2f_lo(wq.y), a3 * b2f_hi(wq.y));
          ak.z = cvtpk(a4 * b2f_lo(wq.z), a5 * b2f_hi(wq.z));
          ak.w = cvtpk(a6 * b2f_lo(wq.w), a7 * b2f_hi(wq.w));
          bf16x8 afrag = __builtin_bit_cast(bf16x8, ak);
          if (k == 0)      acc0 = __builtin_amdgcn_mfma_f32_16x16x32_bf16(afrag, bfrag, acc0, 0, 0, 0);
          else if (k == 1) acc1 = __builtin_amdgcn_mfma_f32_16x16x32_bf16(afrag, bfrag, acc1, 0, 0, 0);
          else if (k == 2) acc2 = __builtin_amdgcn_mfma_f32_16x16x32_bf16(afrag, bfrag, acc2, 0, 0, 0);
          else             acc3 = __builtin_amdgcn_mfma_f32_16x16x32_bf16(afrag, bfrag, acc3, 0, 0, 0);
        }
      }
      // ---- epilogue for this tile (C/D: col = l&15, row = (l>>4)*4 + reg [verified])
      const bool diag = (ti == tj);
      #pragma unroll
      for (int r = 0; r < 4; ++r) {
        const int ib = ti * 16 + lq * 4 + r;
        const int jb = tj * 16 + lc;
        if (ib < 69 && jb < 69 && (!diag || ib <= jb)) {
          const float e0 = acc0[r], e1 = acc1[r], e2 = acc2[r], e3 = acc3[r];
          const int aij = adjld[ib * 70 + jb];
          float sA = (aij <= 1) ? e0 : (aij == 2) ? e1 : (aij == 3) ? e2 : e3;
          sA = (sA >= 0.0f) ? sA : 0.2f * sA;
          if (aij < 1) sA = NEGV;
          dst[b * NN + ib * 69 + jb] = sA;
          const int aji = adjld[jb * 70 + ib];
          float sB = (aji <= 1) ? e0 : (aji == 2) ? e1 : (aji == 3) ? e2 : e3;
          sB = (sB >= 0.0f) ? sB : 0.2f * sB;
          if (aji < 1) sB = NEGV;
          dst[b * NN + jb * 69 + ib] = sB;
        }
      }
    }
  }
}

// ---------------- K4: entmax, 16-lanes-per-row (wave = 4 rows), native v_exp/v_log,
// xor-butterfly reductions (lane-uniform). 20 iters: |tau err| <= dm0*2^-20 ~ 1e-6 ->
// p err <= q*1e-6 ~ 3e-6, ~500x below the remaining tolerance headroom.
__device__ __forceinline__ float pcomp(float xs, float tau, float q) {
  float v = fmaxf(xs - tau, 0.0f);
  return fexp2(q * flog2(v));  // v=0 -> log=-inf -> exp2(-inf)=0
}

__device__ __forceinline__ float bisect20w(const float (&x)[5], float am1, float q) {
  float mx = gmax16(fmaxf(fmaxf(fmaxf(x[0], x[1]), fmaxf(x[2], x[3])), x[4]));
  float tau_lo = mx - 1.0f;
  float tau_hi = mx - fexp2(am1 * flog2(1.0f / 69.0f));  // (1/d)^am1
  float dm = tau_hi - tau_lo;
  float tm = tau_lo;
  #pragma unroll 1
  for (int it = 0; it < 20; ++it) {
    dm *= 0.5f;
    tm = tau_lo + dm;
    float s = pcomp(x[0], tm, q) + pcomp(x[1], tm, q) + pcomp(x[2], tm, q) +
              pcomp(x[3], tm, q) + pcomp(x[4], tm, q);
    s = gsum16(s);
    if (s >= 1.0f) tau_lo = tm;  // butterfly sum is bitwise lane-uniform
  }
  return tm;  // reference uses the last midpoint tau_m for p
}

__global__ __launch_bounds__(256) void k4_entmax(
    const float* __restrict__ alpha, int o,
    float* __restrict__ scA, const float* __restrict__ scB) {
  const int tid = threadIdx.x;
  const int wave = tid >> 6, lane = tid & 63;
  const int grp = lane >> 4, l16 = lane & 15;
  const int row = blockIdx.x * 16 + wave * 4 + grp;  // 0..70655 (4416 blocks)
  const int b = row / 69;
  const float am1A = alpha[o * 1024 + b];
  const float am1B = alpha[2048 + b];
  float* rowA = scA + 69u * (uint)row;
  const float* rowB = scB + 69u * (uint)row;
  // ---- side A
  const float qA = 1.0f / am1A;
  float x[5], pa[5];
  #pragma unroll
  for (int s = 0; s < 5; ++s) {
    int j = s * 16 + l16;
    x[s] = (j < 69) ? rowA[j] * am1A : -1.0e30f;  // pad -> v=0 -> p=0
  }
  const float tA = bisect20w(x, am1A, qA);
  float sA = 0.0f;
  #pragma unroll
  for (int s = 0; s < 5; ++s) { pa[s] = pcomp(x[s], tA, qA); sA += pa[s]; }
  sA = gsum16(sA);
  const float rsA = 1.0f / sA;
  // ---- side B (reuse x registers)
  const float qB = 1.0f / am1B;
  #pragma unroll
  for (int s = 0; s < 5; ++s) {
    int j = s * 16 + l16;
    x[s] = (j < 69) ? rowB[j] * am1B : -1.0e30f;
  }
  const float tB = bisect20w(x, am1B, qB);
  float sB = 0.0f;
  #pragma unroll
  for (int s = 0; s < 5; ++s) { x[s] = pcomp(x[s], tB, qB); sB += x[s]; }
  sB = gsum16(sB);
  const float rsB = 1.0f / sB;
  // ---- combine: w = (pA/sA)*(pB/sB) / (sum + 1e-7)
  float ws = 0.0f;
  #pragma unroll
  for (int s = 0; s < 5; ++s) { x[s] = (pa[s] * rsA) * (x[s] * rsB); ws += x[s]; }
  ws = gsum16(ws);
  const float rden = 1.0f / (ws + 1e-7f);
  #pragma unroll
  for (int s = 0; s < 5; ++s) {
    int j = s * 16 + l16;
    if (j < 69) rowA[j] = x[s] * rden;
  }
}

// ---------------- K5: out = w @ h (w f32 row-major, h f32, out f32)
__global__ __launch_bounds__(256) void k5_out(
    const float* __restrict__ h, const float* __restrict__ wsrc,
    float* __restrict__ outp) {
  const int b = blockIdx.x, tid = threadIdx.x;
  __shared__ float hld[69 * 132];  // 36,432 B
  __shared__ float wld[69 * 70];   // 19,320 B
  for (int idx = tid; idx < 69 * 128; idx += 256) {
    int r = idx >> 7, d = idx & 127;
    hld[r * 132 + d] = h[(b * 69 + r) * 128 + d];
  }
  for (int idx = tid; idx < NN; idx += 256) {
    int i = idx / 69, j = idx - i * 69;
    wld[i * 70 + j] = wsrc[b * NN + idx];
  }
  __syncthreads();
  for (int s = tid; s < 69 * 32; s += 256) {
    int i = s >> 5, dq = s & 31, d0 = dq << 2;
    float acc0 = 0, acc1 = 0, acc2 = 0, acc3 = 0;
    const float* wrow = wld + i * 70;
    const float* hcol = hld + d0;
    for (int j = 0; j < 69; ++j) {
      float wv = wrow[j];
      float4 hv = *(const float4*)(hcol + j * 132);
      acc0 = fmaf(wv, hv.x, acc0);
      acc1 = fmaf(wv, hv.y, acc1);
      acc2 = fmaf(wv, hv.z, acc2);
      acc3 = fmaf(wv, hv.w, acc3);
    }
    float4 ov = make_float4(acc0, acc1, acc2, acc3);
    *(float4*)(outp + (b * 69 + i) * 128 + d0) = ov;
  }
}

extern "C" void kernel_launch(void* const* d_in, const int* in_sizes, int n_in,
                              void* d_out, int out_size, void* d_ws, size_t ws_size,
                              hipStream_t stream) {
  (void)in_sizes; (void)n_in; (void)out_size;
  // Sf32 36,175,872 | alpha 12,288 | scA 19,501,056 | scB 19,501,056 = 75,190,272 B
  if (ws_size < 75190272u) return;  // early-return signature: absmax == 7.08e-2
  const float* in1 = (const float*)d_in[0];
  const float* in2 = (const float*)d_in[1];
  const float* se  = (const float*)d_in[2];
  const int* adjS  = (const int*)d_in[3];
  const int* adjND = (const int*)d_in[4];
  const float* mask = (const float*)d_in[5];
  const int* iidx  = (const int*)d_in[6];
  const float* Wl  = (const float*)d_in[8];
  const float* bl  = (const float*)d_in[9];
  const float* w1p = (const float*)d_in[10];
  const float* b1p = (const float*)d_in[11];
  const float* w2p = (const float*)d_in[12];
  const float* b2p = (const float*)d_in[13];
  const float* wSp = (const float*)d_in[14];
  const float* bSp = (const float*)d_in[15];
  const float* A1  = (const float*)d_in[16];
  const float* S1  = (const float*)d_in[17];
  const float* A2  = (const float*)d_in[18];
  const float* S2  = (const float*)d_in[19];
  float* Sf    = (float*)d_ws;
  float* alpha = (float*)((char*)d_ws + 36175872);
  float* scA   = (float*)((char*)d_ws + 36188160);
  float* scB   = (float*)((char*)d_ws + 55689216);
  float* outp  = (float*)d_out;

  k1_transform<<<dim3(1024), dim3(256), 0, stream>>>(se, Wl, bl, Sf);
  k2_alpha<<<dim3(1024), dim3(128), 0, stream>>>(in1, in2, Sf, mask, iidx,
                                                 w1p, b1p, w2p, b2p, wSp, bSp, alpha);
  // out1
  k3_scores<<<dim3(1024, 2), dim3(256), 0, stream>>>(in1, A1, scA, Sf, S1, scB, adjS);
  k4_entmax<<<dim3(4416), dim3(256), 0, stream>>>(alpha, 0, scA, scB);
  k5_out<<<dim3(1024), dim3(256), 0, stream>>>(in1, scA, outp);
  // out2
  k3_scores<<<dim3(1024, 2), dim3(256), 0, stream>>>(in2, A2, scA, Sf, S2, scB, adjND);
  k4_entmax<<<dim3(4416), dim3(256), 0, stream>>>(alpha, 1, scA, scB);
  k5_out<<<dim3(1024), dim3(256), 0, stream>>>(in2, scA, outp + SZ_S);
}

// Round 13
// 338.123 us; speedup vs baseline: 3.6088x; 1.1461x over previous
//
#include <hip/hip_runtime.h>

typedef unsigned int uint;
typedef unsigned short ushort;
typedef __attribute__((ext_vector_type(8))) short bf16x8;
typedef __attribute__((ext_vector_type(4))) float f32x4;

#define NN 4761            // 69*69
#define SZ_S 9043968       // 1024*69*128
#define NEGV -9000000.0f

// Native single-instruction transcendentals (base-2). v_log_f32(0) = -inf,
// v_exp_f32(-inf) = 0 -> masked elements produce p = 0 exactly.
__device__ __forceinline__ float fexp2(float x) {
  float r; asm("v_exp_f32 %0, %1" : "=v"(r) : "v"(x)); return r;
}
__device__ __forceinline__ float flog2(float x) {
  float r; asm("v_log_f32 %0, %1" : "=v"(r) : "v"(x)); return r;
}
// Packed f32->2xbf16 (RNE). Pack-order convention cancels between A and B operands.
__device__ __forceinline__ uint cvtpk(float lo, float hi) {
  uint r; asm("v_cvt_pk_bf16_f32 %0, %1, %2" : "=v"(r) : "v"(lo), "v"(hi)); return r;
}
__device__ __forceinline__ float b2f_lo(uint u) { return __uint_as_float(u << 16); }
__device__ __forceinline__ float b2f_hi(uint u) { return __uint_as_float(u & 0xFFFF0000u); }
__device__ __forceinline__ ushort f2b(float f) {
  uint x = __float_as_uint(f);
  x += 0x7FFFu + ((x >> 16) & 1u);
  return (ushort)(x >> 16);
}

// 16-lane group reductions via xor-butterfly shuffles (bitwise lane-uniform; see r10
// post-mortem -- DPP row_ror reductions are NOT lane-uniform, caused replay failure).
__device__ __forceinline__ float gsum16(float s) {
  #pragma unroll
  for (int d = 1; d < 16; d <<= 1) s += __shfl_xor(s, d, 16);
  return s;
}
__device__ __forceinline__ float gmax16(float m) {
  #pragma unroll
  for (int d = 1; d < 16; d <<= 1) m = fmaxf(m, __shfl_xor(m, d, 16));
  return m;
}

// ---------------- K0: batch-independent projections for alpha_str.
// v[d] = sum_i wS[i]*W[i][d]  (W^T @ wS); bwS = sum_i bl[i]*wS[i].
// Stored in the alpha buffer: v at [3072..3199], bwS at [3200].
__global__ __launch_bounds__(128) void k0_wproj(
    const float* __restrict__ Wl, const float* __restrict__ bl,
    const float* __restrict__ wSp, float* __restrict__ alpha) {
  __shared__ float red[2];
  const int d = threadIdx.x;
  float v = 0.0f;
  #pragma unroll 8
  for (int i = 0; i < 128; ++i) v = fmaf(wSp[i], Wl[i * 128 + d], v);
  alpha[3072 + d] = v;
  float t = bl[d] * wSp[d];
  for (int off = 32; off >= 1; off >>= 1) t += __shfl_down(t, off);
  if ((d & 63) == 0) red[d >> 6] = t;
  __syncthreads();
  if (d == 0) alpha[3200] = red[0] + red[1];
}

// ---------------- K1 (MFMA): Sb = bf16(se @ W^T + b). 3-term precision split keeps S at
// one-bf16-rounding accuracy: S ~= seh@Wh + sel@Wh + seh@Wr (sel@Wr ~1e-5 rel, dropped).
// Swizzle + fragment mapping identical to k3 (r9-verified). Block=1 batch, 512 thr.
__global__ __launch_bounds__(512) void k1_mfma(
    const float* __restrict__ se, const float* __restrict__ Wl,
    const float* __restrict__ bl, ushort* __restrict__ Sb) {
  __shared__ ushort Hh[80 * 128];   // 20,480 B  bf16(se), swizzled
  __shared__ ushort Hl[80 * 128];   // 20,480 B  bf16(se - bf16(se))
  __shared__ ushort Wh[128 * 128];  // 32,768 B  bf16(W), swizzled
  __shared__ ushort Wr[128 * 128];  // 32,768 B  bf16(W - bf16(W))
  __shared__ float bld[128];
  const int tid = threadIdx.x, b = blockIdx.x;
  for (int idx = tid; idx < 80 * 32; idx += 512) {
    int r = idx >> 5, q = idx & 31, d0 = q << 2;
    uint2 ph, pl;
    if (r < 69) {
      float4 v = *(const float4*)(se + (b * 69 + r) * 128 + d0);
      ph.x = cvtpk(v.x, v.y); ph.y = cvtpk(v.z, v.w);
      float rx = v.x - b2f_lo(ph.x), ry = v.y - b2f_hi(ph.x);
      float rz = v.z - b2f_lo(ph.y), rw = v.w - b2f_hi(ph.y);
      pl.x = cvtpk(rx, ry); pl.y = cvtpk(rz, rw);
    } else { ph.x = 0u; ph.y = 0u; pl.x = 0u; pl.y = 0u; }
    int off = r * 256 + (((d0 >> 3) ^ (r & 7)) << 4) + ((d0 & 7) << 1);
    *(uint2*)((char*)Hh + off) = ph;
    *(uint2*)((char*)Hl + off) = pl;
  }
  for (int idx = tid; idx < 128 * 32; idx += 512) {
    int r = idx >> 5, q = idx & 31, d0 = q << 2;
    float4 v = *(const float4*)(Wl + r * 128 + d0);
    uint2 ph, pl;
    ph.x = cvtpk(v.x, v.y); ph.y = cvtpk(v.z, v.w);
    float rx = v.x - b2f_lo(ph.x), ry = v.y - b2f_hi(ph.x);
    float rz = v.z - b2f_lo(ph.y), rw = v.w - b2f_hi(ph.y);
    pl.x = cvtpk(rx, ry); pl.y = cvtpk(rz, rw);
    int off = r * 256 + (((d0 >> 3) ^ (r & 7)) << 4) + ((d0 & 7) << 1);
    *(uint2*)((char*)Wh + off) = ph;
    *(uint2*)((char*)Wr + off) = pl;
  }
  if (tid < 128) bld[tid] = bl[tid];
  __syncthreads();
  const int wv = tid >> 6, l = tid & 63, lc = l & 15, lq = l >> 4;
  const int rb = wv * 16 + lc;            // W row (col-tile = wave id)
  const float bia = bld[rb];
  for (int rt = 0; rt < 5; ++rt) {
    const int ra = rt * 16 + lc;
    f32x4 acc = {0, 0, 0, 0};
    #pragma unroll
    for (int ks = 0; ks < 4; ++ks) {
      const int d0 = ks * 32 + lq * 8;
      uint4 ah = *(const uint4*)((const char*)Hh + ra * 256 + (((d0 >> 3) ^ (ra & 7)) << 4));
      uint4 al = *(const uint4*)((const char*)Hl + ra * 256 + (((d0 >> 3) ^ (ra & 7)) << 4));
      uint4 bh = *(const uint4*)((const char*)Wh + rb * 256 + (((d0 >> 3) ^ (rb & 7)) << 4));
      uint4 br = *(const uint4*)((const char*)Wr + rb * 256 + (((d0 >> 3) ^ (rb & 7)) << 4));
      acc = __builtin_amdgcn_mfma_f32_16x16x32_bf16(__builtin_bit_cast(bf16x8, ah),
                                                    __builtin_bit_cast(bf16x8, bh), acc, 0, 0, 0);
      acc = __builtin_amdgcn_mfma_f32_16x16x32_bf16(__builtin_bit_cast(bf16x8, al),
                                                    __builtin_bit_cast(bf16x8, bh), acc, 0, 0, 0);
      acc = __builtin_amdgcn_mfma_f32_16x16x32_bf16(__builtin_bit_cast(bf16x8, ah),
                                                    __builtin_bit_cast(bf16x8, br), acc, 0, 0, 0);
    }
    #pragma unroll
    for (int r_ = 0; r_ < 4; ++r_) {
      int ib = rt * 16 + lq * 4 + r_;
      if (ib < 69) Sb[(b * 69 + ib) * 128 + rb] = f2b(acc[r_] + bia);
    }
  }
}

// ---------------- K2: alphas (stores am1): [0..1023]=sem1, [1024..]=sem2, [2048..]=str.
// str-side uses linearity: zS = sum_d u_d*v_d + 2*bwS + bS, u = masked_mean(se)+se_last.
__global__ __launch_bounds__(128) void k2_alpha(
    const float* __restrict__ in1, const float* __restrict__ in2,
    const float* __restrict__ se, const float* __restrict__ mask,
    const int* __restrict__ iidx,
    const float* __restrict__ w1p, const float* __restrict__ b1p,
    const float* __restrict__ w2p, const float* __restrict__ b2p,
    const float* __restrict__ bSp, float* __restrict__ alpha) {
  __shared__ float red[3][2];
  const int b = blockIdx.x, d = threadIdx.x;
  const int last = iidx[b * 69 + 68];
  float a1 = 0, a2 = 0, aS = 0, am = 0;
  const float* p1 = in1 + b * 69 * 128 + d;
  const float* p2 = in2 + b * 69 * 128 + d;
  const float* pS = se + b * 69 * 128 + d;
  const float* pm = mask + b * 69;
  for (int n = 0; n < 69; ++n) {
    float m = pm[n];
    a1 += p1[n * 128] * m;
    a2 += p2[n * 128] * m;
    aS += pS[n * 128] * m;
    am += m;
  }
  float z1 = (a1 / am + p1[last * 128]) * w1p[d];
  float z2 = (a2 / am + p2[last * 128]) * w2p[d];
  float zS = (aS / am + pS[last * 128]) * alpha[3072 + d];  // u_d * v_d
  for (int off = 32; off >= 1; off >>= 1) {
    z1 += __shfl_down(z1, off);
    z2 += __shfl_down(z2, off);
    zS += __shfl_down(zS, off);
  }
  if ((d & 63) == 0) { int wv = d >> 6; red[0][wv] = z1; red[1][wv] = z2; red[2][wv] = zS; }
  __syncthreads();
  if (d == 0) {
    float bwS = alpha[3200];
    float r1 = 1.0f / (1.0f + expf(-(red[0][0] + red[0][1] + b1p[0]))) + 1.0f;
    float r2 = 1.0f / (1.0f + expf(-(red[1][0] + red[1][1] + b2p[0]))) + 1.0f;
    float rS = 1.0f / (1.0f + expf(-(red[2][0] + red[2][1] + 2.0f * bwS + bSp[0]))) + 1.0f;
    if (r1 == 1.0f) r1 = 1.0001f;
    if (r2 == 1.0f) r2 = 1.0001f;
    if (rS == 1.0f) rS = 1.0001f;
    alpha[b] = r1 - 1.0f;
    alpha[1024 + b] = r2 - 1.0f;
    alpha[2048 + b] = rS - 1.0f;
  }
}

// ---------------- K3 (MFMA): E_k = (H o w_k) @ H^T; y=0 sources f32 hA, y=1 sources
// bf16 Sb directly. Symmetric -> 15 upper 16x16 tiles of padded 80x80.
__global__ __launch_bounds__(256) void k3_scores(
    const float* __restrict__ hA, const float* __restrict__ W4A, float* __restrict__ dstA,
    const ushort* __restrict__ Sb, const float* __restrict__ W4B, float* __restrict__ dstB,
    const int* __restrict__ adj) {
  const int b = blockIdx.x, tid = threadIdx.x;
  const int srcS = blockIdx.y;
  const float* W4 = srcS ? W4B : W4A;
  float* dst      = srcS ? dstB : dstA;
  __shared__ ushort Hb[80 * 128];       // bf16, row pitch 256 B, XOR-swizzled chunks
  __shared__ uint W4b[4 * 64];          // bf16-packed W4
  __shared__ signed char adjld[69 * 70];
  for (int idx = tid; idx < 80 * 32; idx += 256) {
    int r = idx >> 5, q = idx & 31, d0 = q << 2;
    uint2 pk;
    if (r < 69) {
      if (srcS) {
        pk = *(const uint2*)(Sb + (b * 69 + r) * 128 + d0);
      } else {
        float4 v = *(const float4*)(hA + (b * 69 + r) * 128 + d0);
        pk.x = cvtpk(v.x, v.y);
        pk.y = cvtpk(v.z, v.w);
      }
    } else { pk.x = 0u; pk.y = 0u; }
    *(uint2*)((char*)Hb + r * 256 + (((d0 >> 3) ^ (r & 7)) << 4) + ((d0 & 7) << 1)) = pk;
  }
  {
    int k = tid >> 6, dp = (tid & 63) << 1;
    W4b[k * 64 + (tid & 63)] = cvtpk(W4[k * 128 + dp], W4[k * 128 + dp + 1]);
  }
  for (int idx = tid; idx < NN; idx += 256)
    adjld[(idx / 69) * 70 + (idx % 69)] = (signed char)adj[b * NN + idx];
  __syncthreads();
  const int wv = tid >> 6, l = tid & 63;
  const int lc = l & 15, lq = l >> 4;
  #pragma unroll
  for (int s = 0; s < 4; ++s) {
    const int id = wv + 4 * s;
    if (id < 15) {
      const int ti = (id < 5) ? 0 : (id < 9) ? 1 : (id < 12) ? 2 : (id < 14) ? 3 : 4;
      const int base = (ti == 0) ? 0 : (ti == 1) ? 5 : (ti == 2) ? 9 : (ti == 3) ? 12 : 14;
      const int tj = ti + (id - base);
      const int ra = ti * 16 + lc, rb = tj * 16 + lc;
      f32x4 acc0 = {0,0,0,0}, acc1 = {0,0,0,0}, acc2 = {0,0,0,0}, acc3 = {0,0,0,0};
      #pragma unroll
      for (int ks = 0; ks < 4; ++ks) {
        const int d0 = ks * 32 + lq * 8;
        uint4 araw = *(const uint4*)((const char*)Hb + ra * 256 + (((d0 >> 3) ^ (ra & 7)) << 4));
        uint4 braw = *(const uint4*)((const char*)Hb + rb * 256 + (((d0 >> 3) ^ (rb & 7)) << 4));
        float a0 = b2f_lo(araw.x), a1 = b2f_hi(araw.x);
        float a2 = b2f_lo(araw.y), a3 = b2f_hi(araw.y);
        float a4 = b2f_lo(araw.z), a5 = b2f_hi(araw.z);
        float a6 = b2f_lo(araw.w), a7 = b2f_hi(araw.w);
        bf16x8 bfrag = __builtin_bit_cast(bf16x8, braw);
        #pragma unroll
        for (int k = 0; k < 4; ++k) {
          uint4 wq = *(const uint4*)(W4b + k * 64 + (d0 >> 1));
          uint4 ak;
          ak.x = cvtpk(a0 * b2f_lo(wq.x), a1 * b2f_hi(wq.x));
          ak.y = cvtpk(a2 * b2f_lo(wq.y), a3 * b2f_hi(wq.y));
          ak.z = cvtpk(a4 * b2f_lo(wq.z), a5 * b2f_hi(wq.z));
          ak.w = cvtpk(a6 * b2f_lo(wq.w), a7 * b2f_hi(wq.w));
          bf16x8 afrag = __builtin_bit_cast(bf16x8, ak);
          if (k == 0)      acc0 = __builtin_amdgcn_mfma_f32_16x16x32_bf16(afrag, bfrag, acc0, 0, 0, 0);
          else if (k == 1) acc1 = __builtin_amdgcn_mfma_f32_16x16x32_bf16(afrag, bfrag, acc1, 0, 0, 0);
          else if (k == 2) acc2 = __builtin_amdgcn_mfma_f32_16x16x32_bf16(afrag, bfrag, acc2, 0, 0, 0);
          else             acc3 = __builtin_amdgcn_mfma_f32_16x16x32_bf16(afrag, bfrag, acc3, 0, 0, 0);
        }
      }
      const bool diag = (ti == tj);
      #pragma unroll
      for (int r = 0; r < 4; ++r) {
        const int ib = ti * 16 + lq * 4 + r;
        const int jb = tj * 16 + lc;
        if (ib < 69 && jb < 69 && (!diag || ib <= jb)) {
          const float e0 = acc0[r], e1 = acc1[r], e2 = acc2[r], e3 = acc3[r];
          const int aij = adjld[ib * 70 + jb];
          float sA = (aij <= 1) ? e0 : (aij == 2) ? e1 : (aij == 3) ? e2 : e3;
          sA = (sA >= 0.0f) ? sA : 0.2f * sA;
          if (aij < 1) sA = NEGV;
          dst[b * NN + ib * 69 + jb] = sA;
          const int aji = adjld[jb * 70 + ib];
          float sB = (aji <= 1) ? e0 : (aji == 2) ? e1 : (aji == 3) ? e2 : e3;
          sB = (sB >= 0.0f) ? sB : 0.2f * sB;
          if (aji < 1) sB = NEGV;
          dst[b * NN + jb * 69 + ib] = sB;
        }
      }
    }
  }
}

// ---------------- K4: entmax, 16-lanes-per-row (wave = 4 rows), native v_exp/v_log,
// xor-butterfly reductions (lane-uniform). 20 iters: tau err <= 1e-6 -> p err ~3e-6.
__device__ __forceinline__ float pcomp(float xs, float tau, float q) {
  float v = fmaxf(xs - tau, 0.0f);
  return fexp2(q * flog2(v));  // v=0 -> log=-inf -> exp2(-inf)=0
}

__device__ __forceinline__ float bisect20w(const float (&x)[5], float am1, float q) {
  float mx = gmax16(fmaxf(fmaxf(fmaxf(x[0], x[1]), fmaxf(x[2], x[3])), x[4]));
  float tau_lo = mx - 1.0f;
  float tau_hi = mx - fexp2(am1 * flog2(1.0f / 69.0f));  // (1/d)^am1
  float dm = tau_hi - tau_lo;
  float tm = tau_lo;
  #pragma unroll 1
  for (int it = 0; it < 20; ++it) {
    dm *= 0.5f;
    tm = tau_lo + dm;
    float s = pcomp(x[0], tm, q) + pcomp(x[1], tm, q) + pcomp(x[2], tm, q) +
              pcomp(x[3], tm, q) + pcomp(x[4], tm, q);
    s = gsum16(s);
    if (s >= 1.0f) tau_lo = tm;  // butterfly sum is bitwise lane-uniform
  }
  return tm;  // reference uses the last midpoint tau_m for p
}

__global__ __launch_bounds__(256) void k4_entmax(
    const float* __restrict__ alpha, int o,
    float* __restrict__ scA, const float* __restrict__ scB) {
  const int tid = threadIdx.x;
  const int wave = tid >> 6, lane = tid & 63;
  const int grp = lane >> 4, l16 = lane & 15;
  const int row = blockIdx.x * 16 + wave * 4 + grp;  // 0..70655 (4416 blocks)
  const int b = row / 69;
  const float am1A = alpha[o * 1024 + b];
  const float am1B = alpha[2048 + b];
  float* rowA = scA + 69u * (uint)row;
  const float* rowB = scB + 69u * (uint)row;
  const float qA = 1.0f / am1A;
  float x[5], pa[5];
  #pragma unroll
  for (int s = 0; s < 5; ++s) {
    int j = s * 16 + l16;
    x[s] = (j < 69) ? rowA[j] * am1A : -1.0e30f;  // pad -> v=0 -> p=0
  }
  const float tA = bisect20w(x, am1A, qA);
  float sA = 0.0f;
  #pragma unroll
  for (int s = 0; s < 5; ++s) { pa[s] = pcomp(x[s], tA, qA); sA += pa[s]; }
  sA = gsum16(sA);
  const float rsA = 1.0f / sA;
  const float qB = 1.0f / am1B;
  #pragma unroll
  for (int s = 0; s < 5; ++s) {
    int j = s * 16 + l16;
    x[s] = (j < 69) ? rowB[j] * am1B : -1.0e30f;
  }
  const float tB = bisect20w(x, am1B, qB);
  float sB = 0.0f;
  #pragma unroll
  for (int s = 0; s < 5; ++s) { x[s] = pcomp(x[s], tB, qB); sB += x[s]; }
  sB = gsum16(sB);
  const float rsB = 1.0f / sB;
  float ws = 0.0f;
  #pragma unroll
  for (int s = 0; s < 5; ++s) { x[s] = (pa[s] * rsA) * (x[s] * rsB); ws += x[s]; }
  ws = gsum16(ws);
  const float rden = 1.0f / (ws + 1e-7f);
  #pragma unroll
  for (int s = 0; s < 5; ++s) {
    int j = s * 16 + l16;
    if (j < 69) rowA[j] = x[s] * rden;
  }
}

// ---------------- K5: out = w @ h (w f32 row-major, h f32, out f32)
__global__ __launch_bounds__(256) void k5_out(
    const float* __restrict__ h, const float* __restrict__ wsrc,
    float* __restrict__ outp) {
  const int b = blockIdx.x, tid = threadIdx.x;
  __shared__ float hld[69 * 132];  // 36,432 B
  __shared__ float wld[69 * 70];   // 19,320 B
  for (int idx = tid; idx < 69 * 128; idx += 256) {
    int r = idx >> 7, d = idx & 127;
    hld[r * 132 + d] = h[(b * 69 + r) * 128 + d];
  }
  for (int idx = tid; idx < NN; idx += 256) {
    int i = idx / 69, j = idx - i * 69;
    wld[i * 70 + j] = wsrc[b * NN + idx];
  }
  __syncthreads();
  for (int s = tid; s < 69 * 32; s += 256) {
    int i = s >> 5, dq = s & 31, d0 = dq << 2;
    float acc0 = 0, acc1 = 0, acc2 = 0, acc3 = 0;
    const float* wrow = wld + i * 70;
    const float* hcol = hld + d0;
    for (int j = 0; j < 69; ++j) {
      float wv = wrow[j];
      float4 hv = *(const float4*)(hcol + j * 132);
      acc0 = fmaf(wv, hv.x, acc0);
      acc1 = fmaf(wv, hv.y, acc1);
      acc2 = fmaf(wv, hv.z, acc2);
      acc3 = fmaf(wv, hv.w, acc3);
    }
    float4 ov = make_float4(acc0, acc1, acc2, acc3);
    *(float4*)(outp + (b * 69 + i) * 128 + d0) = ov;
  }
}

extern "C" void kernel_launch(void* const* d_in, const int* in_sizes, int n_in,
                              void* d_out, int out_size, void* d_ws, size_t ws_size,
                              hipStream_t stream) {
  (void)in_sizes; (void)n_in; (void)out_size;
  // Sb(bf16) 18,087,936 | alpha 16,384 | scA 19,501,056 | scB 19,501,056 = 57,106,432 B
  if (ws_size < 57106432u) return;  // early-return signature: absmax == 7.08e-2
  const float* in1 = (const float*)d_in[0];
  const float* in2 = (const float*)d_in[1];
  const float* se  = (const float*)d_in[2];
  const int* adjS  = (const int*)d_in[3];
  const int* adjND = (const int*)d_in[4];
  const float* mask = (const float*)d_in[5];
  const int* iidx  = (const int*)d_in[6];
  const float* Wl  = (const float*)d_in[8];
  const float* bl  = (const float*)d_in[9];
  const float* w1p = (const float*)d_in[10];
  const float* b1p = (const float*)d_in[11];
  const float* w2p = (const float*)d_in[12];
  const float* b2p = (const float*)d_in[13];
  const float* wSp = (const float*)d_in[14];
  const float* bSp = (const float*)d_in[15];
  const float* A1  = (const float*)d_in[16];
  const float* S1  = (const float*)d_in[17];
  const float* A2  = (const float*)d_in[18];
  const float* S2  = (const float*)d_in[19];
  ushort* Sb   = (ushort*)d_ws;
  float* alpha = (float*)((char*)d_ws + 18087936);
  float* scA   = (float*)((char*)d_ws + 18104320);
  float* scB   = (float*)((char*)d_ws + 37605376);
  float* outp  = (float*)d_out;

  k0_wproj<<<dim3(1), dim3(128), 0, stream>>>(Wl, bl, wSp, alpha);
  k1_mfma<<<dim3(1024), dim3(512), 0, stream>>>(se, Wl, bl, Sb);
  k2_alpha<<<dim3(1024), dim3(128), 0, stream>>>(in1, in2, se, mask, iidx,
                                                 w1p, b1p, w2p, b2p, bSp, alpha);
  // out1
  k3_scores<<<dim3(1024, 2), dim3(256), 0, stream>>>(in1, A1, scA, Sb, S1, scB, adjS);
  k4_entmax<<<dim3(4416), dim3(256), 0, stream>>>(alpha, 0, scA, scB);
  k5_out<<<dim3(1024), dim3(256), 0, stream>>>(in1, scA, outp);
  // out2
  k3_scores<<<dim3(1024, 2), dim3(256), 0, stream>>>(in2, A2, scA, Sb, S2, scB, adjND);
  k4_entmax<<<dim3(4416), dim3(256), 0, stream>>>(alpha, 1, scA, scB);
  k5_out<<<dim3(1024), dim3(256), 0, stream>>>(in2, scA, outp + SZ_S);
}

// Round 14
// 309.718 us; speedup vs baseline: 3.9398x; 1.0917x over previous
//
#include <hip/hip_runtime.h>

typedef unsigned int uint;
typedef unsigned short ushort;
typedef __attribute__((ext_vector_type(8))) short bf16x8;
typedef __attribute__((ext_vector_type(4))) float f32x4;

#define NN 4761            // 69*69
#define SZ_S 9043968       // 1024*69*128
#define NEGV -9000000.0f

// Native single-instruction transcendentals (base-2). v_log_f32(0) = -inf,
// v_exp_f32(-inf) = 0 -> masked elements produce p = 0 exactly.
__device__ __forceinline__ float fexp2(float x) {
  float r; asm("v_exp_f32 %0, %1" : "=v"(r) : "v"(x)); return r;
}
__device__ __forceinline__ float flog2(float x) {
  float r; asm("v_log_f32 %0, %1" : "=v"(r) : "v"(x)); return r;
}
// Packed f32->2xbf16 (RNE). Pack-order convention cancels between A and B operands.
__device__ __forceinline__ uint cvtpk(float lo, float hi) {
  uint r; asm("v_cvt_pk_bf16_f32 %0, %1, %2" : "=v"(r) : "v"(lo), "v"(hi)); return r;
}
__device__ __forceinline__ float b2f_lo(uint u) { return __uint_as_float(u << 16); }
__device__ __forceinline__ float b2f_hi(uint u) { return __uint_as_float(u & 0xFFFF0000u); }
__device__ __forceinline__ ushort f2b(float f) {
  uint x = __float_as_uint(f);
  x += 0x7FFFu + ((x >> 16) & 1u);
  return (ushort)(x >> 16);
}

// 16-lane group reductions via xor-butterfly shuffles (bitwise lane-uniform; see r10
// post-mortem -- DPP row_ror reductions are NOT lane-uniform, caused replay failure).
__device__ __forceinline__ float gsum16(float s) {
  #pragma unroll
  for (int d = 1; d < 16; d <<= 1) s += __shfl_xor(s, d, 16);
  return s;
}
__device__ __forceinline__ float gmax16(float m) {
  #pragma unroll
  for (int d = 1; d < 16; d <<= 1) m = fmaxf(m, __shfl_xor(m, d, 16));
  return m;
}

// ---------------- K0: batch-independent projections for alpha_str.
// v[d] = sum_i wS[i]*W[i][d]  (W^T @ wS); bwS = sum_i bl[i]*wS[i].
// Stored in the alpha buffer: v at [3072..3199], bwS at [3200].
__global__ __launch_bounds__(128) void k0_wproj(
    const float* __restrict__ Wl, const float* __restrict__ bl,
    const float* __restrict__ wSp, float* __restrict__ alpha) {
  __shared__ float red[2];
  const int d = threadIdx.x;
  float v = 0.0f;
  #pragma unroll 8
  for (int i = 0; i < 128; ++i) v = fmaf(wSp[i], Wl[i * 128 + d], v);
  alpha[3072 + d] = v;
  float t = bl[d] * wSp[d];
  for (int off = 32; off >= 1; off >>= 1) t += __shfl_down(t, off);
  if ((d & 63) == 0) red[d >> 6] = t;
  __syncthreads();
  if (d == 0) alpha[3200] = red[0] + red[1];
}

// ---------------- K1 (MFMA): Sb = bf16(se @ W^T + b). 3-term precision split keeps S at
// one-bf16-rounding accuracy: S ~= seh@Wh + sel@Wh + seh@Wr (sel@Wr ~1e-5 rel, dropped).
__global__ __launch_bounds__(512) void k1_mfma(
    const float* __restrict__ se, const float* __restrict__ Wl,
    const float* __restrict__ bl, ushort* __restrict__ Sb) {
  __shared__ ushort Hh[80 * 128];   // 20,480 B  bf16(se), swizzled
  __shared__ ushort Hl[80 * 128];   // 20,480 B  bf16(se - bf16(se))
  __shared__ ushort Wh[128 * 128];  // 32,768 B  bf16(W), swizzled
  __shared__ ushort Wr[128 * 128];  // 32,768 B  bf16(W - bf16(W))
  __shared__ float bld[128];
  const int tid = threadIdx.x, b = blockIdx.x;
  for (int idx = tid; idx < 80 * 32; idx += 512) {
    int r = idx >> 5, q = idx & 31, d0 = q << 2;
    uint2 ph, pl;
    if (r < 69) {
      float4 v = *(const float4*)(se + (b * 69 + r) * 128 + d0);
      ph.x = cvtpk(v.x, v.y); ph.y = cvtpk(v.z, v.w);
      float rx = v.x - b2f_lo(ph.x), ry = v.y - b2f_hi(ph.x);
      float rz = v.z - b2f_lo(ph.y), rw = v.w - b2f_hi(ph.y);
      pl.x = cvtpk(rx, ry); pl.y = cvtpk(rz, rw);
    } else { ph.x = 0u; ph.y = 0u; pl.x = 0u; pl.y = 0u; }
    int off = r * 256 + (((d0 >> 3) ^ (r & 7)) << 4) + ((d0 & 7) << 1);
    *(uint2*)((char*)Hh + off) = ph;
    *(uint2*)((char*)Hl + off) = pl;
  }
  for (int idx = tid; idx < 128 * 32; idx += 512) {
    int r = idx >> 5, q = idx & 31, d0 = q << 2;
    float4 v = *(const float4*)(Wl + r * 128 + d0);
    uint2 ph, pl;
    ph.x = cvtpk(v.x, v.y); ph.y = cvtpk(v.z, v.w);
    float rx = v.x - b2f_lo(ph.x), ry = v.y - b2f_hi(ph.x);
    float rz = v.z - b2f_lo(ph.y), rw = v.w - b2f_hi(ph.y);
    pl.x = cvtpk(rx, ry); pl.y = cvtpk(rz, rw);
    int off = r * 256 + (((d0 >> 3) ^ (r & 7)) << 4) + ((d0 & 7) << 1);
    *(uint2*)((char*)Wh + off) = ph;
    *(uint2*)((char*)Wr + off) = pl;
  }
  if (tid < 128) bld[tid] = bl[tid];
  __syncthreads();
  const int wv = tid >> 6, l = tid & 63, lc = l & 15, lq = l >> 4;
  const int rb = wv * 16 + lc;            // W row (col-tile = wave id)
  const float bia = bld[rb];
  for (int rt = 0; rt < 5; ++rt) {
    const int ra = rt * 16 + lc;
    f32x4 acc = {0, 0, 0, 0};
    #pragma unroll
    for (int ks = 0; ks < 4; ++ks) {
      const int d0 = ks * 32 + lq * 8;
      uint4 ah = *(const uint4*)((const char*)Hh + ra * 256 + (((d0 >> 3) ^ (ra & 7)) << 4));
      uint4 al = *(const uint4*)((const char*)Hl + ra * 256 + (((d0 >> 3) ^ (ra & 7)) << 4));
      uint4 bh = *(const uint4*)((const char*)Wh + rb * 256 + (((d0 >> 3) ^ (rb & 7)) << 4));
      uint4 br = *(const uint4*)((const char*)Wr + rb * 256 + (((d0 >> 3) ^ (rb & 7)) << 4));
      acc = __builtin_amdgcn_mfma_f32_16x16x32_bf16(__builtin_bit_cast(bf16x8, ah),
                                                    __builtin_bit_cast(bf16x8, bh), acc, 0, 0, 0);
      acc = __builtin_amdgcn_mfma_f32_16x16x32_bf16(__builtin_bit_cast(bf16x8, al),
                                                    __builtin_bit_cast(bf16x8, bh), acc, 0, 0, 0);
      acc = __builtin_amdgcn_mfma_f32_16x16x32_bf16(__builtin_bit_cast(bf16x8, ah),
                                                    __builtin_bit_cast(bf16x8, br), acc, 0, 0, 0);
    }
    #pragma unroll
    for (int r_ = 0; r_ < 4; ++r_) {
      int ib = rt * 16 + lq * 4 + r_;
      if (ib < 69) Sb[(b * 69 + ib) * 128 + rb] = f2b(acc[r_] + bia);
    }
  }
}

// ---------------- K2: alphas (stores am1): [0..1023]=sem1, [1024..]=sem2, [2048..]=str.
__global__ __launch_bounds__(128) void k2_alpha(
    const float* __restrict__ in1, const float* __restrict__ in2,
    const float* __restrict__ se, const float* __restrict__ mask,
    const int* __restrict__ iidx,
    const float* __restrict__ w1p, const float* __restrict__ b1p,
    const float* __restrict__ w2p, const float* __restrict__ b2p,
    const float* __restrict__ bSp, float* __restrict__ alpha) {
  __shared__ float red[3][2];
  const int b = blockIdx.x, d = threadIdx.x;
  const int last = iidx[b * 69 + 68];
  float a1 = 0, a2 = 0, aS = 0, am = 0;
  const float* p1 = in1 + b * 69 * 128 + d;
  const float* p2 = in2 + b * 69 * 128 + d;
  const float* pS = se + b * 69 * 128 + d;
  const float* pm = mask + b * 69;
  for (int n = 0; n < 69; ++n) {
    float m = pm[n];
    a1 += p1[n * 128] * m;
    a2 += p2[n * 128] * m;
    aS += pS[n * 128] * m;
    am += m;
  }
  float z1 = (a1 / am + p1[last * 128]) * w1p[d];
  float z2 = (a2 / am + p2[last * 128]) * w2p[d];
  float zS = (aS / am + pS[last * 128]) * alpha[3072 + d];  // u_d * v_d
  for (int off = 32; off >= 1; off >>= 1) {
    z1 += __shfl_down(z1, off);
    z2 += __shfl_down(z2, off);
    zS += __shfl_down(zS, off);
  }
  if ((d & 63) == 0) { int wv = d >> 6; red[0][wv] = z1; red[1][wv] = z2; red[2][wv] = zS; }
  __syncthreads();
  if (d == 0) {
    float bwS = alpha[3200];
    float r1 = 1.0f / (1.0f + expf(-(red[0][0] + red[0][1] + b1p[0]))) + 1.0f;
    float r2 = 1.0f / (1.0f + expf(-(red[1][0] + red[1][1] + b2p[0]))) + 1.0f;
    float rS = 1.0f / (1.0f + expf(-(red[2][0] + red[2][1] + 2.0f * bwS + bSp[0]))) + 1.0f;
    if (r1 == 1.0f) r1 = 1.0001f;
    if (r2 == 1.0f) r2 = 1.0001f;
    if (rS == 1.0f) rS = 1.0001f;
    alpha[b] = r1 - 1.0f;
    alpha[1024 + b] = r2 - 1.0f;
    alpha[2048 + b] = rS - 1.0f;
  }
}

// ---------------- K3 (MFMA): E_k = (H o w_k) @ H^T; y=0 sources f32 hA, y=1 sources
// bf16 Sb directly. Symmetric -> 15 upper 16x16 tiles of padded 80x80.
__global__ __launch_bounds__(256) void k3_scores(
    const float* __restrict__ hA, const float* __restrict__ W4A, float* __restrict__ dstA,
    const ushort* __restrict__ Sb, const float* __restrict__ W4B, float* __restrict__ dstB,
    const int* __restrict__ adj) {
  const int b = blockIdx.x, tid = threadIdx.x;
  const int srcS = blockIdx.y;
  const float* W4 = srcS ? W4B : W4A;
  float* dst      = srcS ? dstB : dstA;
  __shared__ ushort Hb[80 * 128];       // bf16, row pitch 256 B, XOR-swizzled chunks
  __shared__ uint W4b[4 * 64];          // bf16-packed W4
  __shared__ signed char adjld[69 * 70];
  for (int idx = tid; idx < 80 * 32; idx += 256) {
    int r = idx >> 5, q = idx & 31, d0 = q << 2;
    uint2 pk;
    if (r < 69) {
      if (srcS) {
        pk = *(const uint2*)(Sb + (b * 69 + r) * 128 + d0);
      } else {
        float4 v = *(const float4*)(hA + (b * 69 + r) * 128 + d0);
        pk.x = cvtpk(v.x, v.y);
        pk.y = cvtpk(v.z, v.w);
      }
    } else { pk.x = 0u; pk.y = 0u; }
    *(uint2*)((char*)Hb + r * 256 + (((d0 >> 3) ^ (r & 7)) << 4) + ((d0 & 7) << 1)) = pk;
  }
  {
    int k = tid >> 6, dp = (tid & 63) << 1;
    W4b[k * 64 + (tid & 63)] = cvtpk(W4[k * 128 + dp], W4[k * 128 + dp + 1]);
  }
  for (int idx = tid; idx < NN; idx += 256)
    adjld[(idx / 69) * 70 + (idx % 69)] = (signed char)adj[b * NN + idx];
  __syncthreads();
  const int wv = tid >> 6, l = tid & 63;
  const int lc = l & 15, lq = l >> 4;
  #pragma unroll
  for (int s = 0; s < 4; ++s) {
    const int id = wv + 4 * s;
    if (id < 15) {
      const int ti = (id < 5) ? 0 : (id < 9) ? 1 : (id < 12) ? 2 : (id < 14) ? 3 : 4;
      const int base = (ti == 0) ? 0 : (ti == 1) ? 5 : (ti == 2) ? 9 : (ti == 3) ? 12 : 14;
      const int tj = ti + (id - base);
      const int ra = ti * 16 + lc, rb = tj * 16 + lc;
      f32x4 acc0 = {0,0,0,0}, acc1 = {0,0,0,0}, acc2 = {0,0,0,0}, acc3 = {0,0,0,0};
      #pragma unroll
      for (int ks = 0; ks < 4; ++ks) {
        const int d0 = ks * 32 + lq * 8;
        uint4 araw = *(const uint4*)((const char*)Hb + ra * 256 + (((d0 >> 3) ^ (ra & 7)) << 4));
        uint4 braw = *(const uint4*)((const char*)Hb + rb * 256 + (((d0 >> 3) ^ (rb & 7)) << 4));
        float a0 = b2f_lo(araw.x), a1 = b2f_hi(araw.x);
        float a2 = b2f_lo(araw.y), a3 = b2f_hi(araw.y);
        float a4 = b2f_lo(araw.z), a5 = b2f_hi(araw.z);
        float a6 = b2f_lo(araw.w), a7 = b2f_hi(araw.w);
        bf16x8 bfrag = __builtin_bit_cast(bf16x8, braw);
        #pragma unroll
        for (int k = 0; k < 4; ++k) {
          uint4 wq = *(const uint4*)(W4b + k * 64 + (d0 >> 1));
          uint4 ak;
          ak.x = cvtpk(a0 * b2f_lo(wq.x), a1 * b2f_hi(wq.x));
          ak.y = cvtpk(a2 * b2f_lo(wq.y), a3 * b2f_hi(wq.y));
          ak.z = cvtpk(a4 * b2f_lo(wq.z), a5 * b2f_hi(wq.z));
          ak.w = cvtpk(a6 * b2f_lo(wq.w), a7 * b2f_hi(wq.w));
          bf16x8 afrag = __builtin_bit_cast(bf16x8, ak);
          if (k == 0)      acc0 = __builtin_amdgcn_mfma_f32_16x16x32_bf16(afrag, bfrag, acc0, 0, 0, 0);
          else if (k == 1) acc1 = __builtin_amdgcn_mfma_f32_16x16x32_bf16(afrag, bfrag, acc1, 0, 0, 0);
          else if (k == 2) acc2 = __builtin_amdgcn_mfma_f32_16x16x32_bf16(afrag, bfrag, acc2, 0, 0, 0);
          else             acc3 = __builtin_amdgcn_mfma_f32_16x16x32_bf16(afrag, bfrag, acc3, 0, 0, 0);
        }
      }
      const bool diag = (ti == tj);
      #pragma unroll
      for (int r = 0; r < 4; ++r) {
        const int ib = ti * 16 + lq * 4 + r;
        const int jb = tj * 16 + lc;
        if (ib < 69 && jb < 69 && (!diag || ib <= jb)) {
          const float e0 = acc0[r], e1 = acc1[r], e2 = acc2[r], e3 = acc3[r];
          const int aij = adjld[ib * 70 + jb];
          float sA = (aij <= 1) ? e0 : (aij == 2) ? e1 : (aij == 3) ? e2 : e3;
          sA = (sA >= 0.0f) ? sA : 0.2f * sA;
          if (aij < 1) sA = NEGV;
          dst[b * NN + ib * 69 + jb] = sA;
          const int aji = adjld[jb * 70 + ib];
          float sB = (aji <= 1) ? e0 : (aji == 2) ? e1 : (aji == 3) ? e2 : e3;
          sB = (sB >= 0.0f) ? sB : 0.2f * sB;
          if (aji < 1) sB = NEGV;
          dst[b * NN + jb * 69 + ib] = sB;
        }
      }
    }
  }
}

// ---------------- K4: entmax, 16-lanes-per-row (wave = 4 rows), native v_exp/v_log,
// xor-butterfly reductions (lane-uniform). 15 iters (|tau err| <= 2.8e-5 -> p err
// <= 7e-5, well under tolerance headroom). The final p-sweep is fused into the loop:
// the returned tau IS the last midpoint, so the last iteration's p's and group-sum
// ARE the final values (bitwise identical to a recompute) -- saves one 5-pcomp sweep
// + one gsum16 per side.
__device__ __forceinline__ float pcomp(float xs, float tau, float q) {
  float v = fmaxf(xs - tau, 0.0f);
  return fexp2(q * flog2(v));  // v=0 -> log=-inf -> exp2(-inf)=0
}

// In: x = scaled scores. Out: x = p values at the final tau; returns group-sum of p.
__device__ __forceinline__ float bisect15w(float (&x)[5], float am1, float q) {
  float mx = gmax16(fmaxf(fmaxf(fmaxf(x[0], x[1]), fmaxf(x[2], x[3])), x[4]));
  float tau_lo = mx - 1.0f;
  float tau_hi = mx - fexp2(am1 * flog2(1.0f / 69.0f));  // (1/d)^am1
  float dm = tau_hi - tau_lo;
  float p0 = 0, p1 = 0, p2 = 0, p3 = 0, p4 = 0, s = 0;
  #pragma unroll 1
  for (int it = 0; it < 15; ++it) {
    dm *= 0.5f;
    const float tm = tau_lo + dm;
    p0 = pcomp(x[0], tm, q);
    p1 = pcomp(x[1], tm, q);
    p2 = pcomp(x[2], tm, q);
    p3 = pcomp(x[3], tm, q);
    p4 = pcomp(x[4], tm, q);
    s = gsum16(p0 + p1 + p2 + p3 + p4);
    if (s >= 1.0f) tau_lo = tm;  // butterfly sum is bitwise lane-uniform
  }
  x[0] = p0; x[1] = p1; x[2] = p2; x[3] = p3; x[4] = p4;
  return s;
}

__global__ __launch_bounds__(256) void k4_entmax(
    const float* __restrict__ alpha, int o,
    float* __restrict__ scA, const float* __restrict__ scB) {
  const int tid = threadIdx.x;
  const int wave = tid >> 6, lane = tid & 63;
  const int grp = lane >> 4, l16 = lane & 15;
  const int row = blockIdx.x * 16 + wave * 4 + grp;  // 0..70655 (4416 blocks)
  const int b = row / 69;
  const float am1A = alpha[o * 1024 + b];
  const float am1B = alpha[2048 + b];
  float* rowA = scA + 69u * (uint)row;
  const float* rowB = scB + 69u * (uint)row;
  // ---- side A: bisect; x becomes p_A
  const float qA = 1.0f / am1A;
  float x[5], pa[5];
  #pragma unroll
  for (int s = 0; s < 5; ++s) {
    int j = s * 16 + l16;
    x[s] = (j < 69) ? rowA[j] * am1A : -1.0e30f;  // pad -> v=0 -> p=0
  }
  const float sA = bisect15w(x, am1A, qA);
  const float rsA = 1.0f / sA;
  #pragma unroll
  for (int s = 0; s < 5; ++s) pa[s] = x[s];
  // ---- side B (reuse x registers): x becomes p_B
  const float qB = 1.0f / am1B;
  #pragma unroll
  for (int s = 0; s < 5; ++s) {
    int j = s * 16 + l16;
    x[s] = (j < 69) ? rowB[j] * am1B : -1.0e30f;
  }
  const float sB = bisect15w(x, am1B, qB);
  const float rsB = 1.0f / sB;
  // ---- combine: w = (pA/sA)*(pB/sB) / (sum + 1e-7)
  float ws = 0.0f;
  #pragma unroll
  for (int s = 0; s < 5; ++s) { x[s] = (pa[s] * rsA) * (x[s] * rsB); ws += x[s]; }
  ws = gsum16(ws);
  const float rden = 1.0f / (ws + 1e-7f);
  #pragma unroll
  for (int s = 0; s < 5; ++s) {
    int j = s * 16 + l16;
    if (j < 69) rowA[j] = x[s] * rden;
  }
}

// ---------------- K5: out = w @ h (w f32 row-major, h f32, out f32)
__global__ __launch_bounds__(256) void k5_out(
    const float* __restrict__ h, const float* __restrict__ wsrc,
    float* __restrict__ outp) {
  const int b = blockIdx.x, tid = threadIdx.x;
  __shared__ float hld[69 * 132];  // 36,432 B
  __shared__ float wld[69 * 70];   // 19,320 B
  for (int idx = tid; idx < 69 * 128; idx += 256) {
    int r = idx >> 7, d = idx & 127;
    hld[r * 132 + d] = h[(b * 69 + r) * 128 + d];
  }
  for (int idx = tid; idx < NN; idx += 256) {
    int i = idx / 69, j = idx - i * 69;
    wld[i * 70 + j] = wsrc[b * NN + idx];
  }
  __syncthreads();
  for (int s = tid; s < 69 * 32; s += 256) {
    int i = s >> 5, dq = s & 31, d0 = dq << 2;
    float acc0 = 0, acc1 = 0, acc2 = 0, acc3 = 0;
    const float* wrow = wld + i * 70;
    const float* hcol = hld + d0;
    for (int j = 0; j < 69; ++j) {
      float wv = wrow[j];
      float4 hv = *(const float4*)(hcol + j * 132);
      acc0 = fmaf(wv, hv.x, acc0);
      acc1 = fmaf(wv, hv.y, acc1);
      acc2 = fmaf(wv, hv.z, acc2);
      acc3 = fmaf(wv, hv.w, acc3);
    }
    float4 ov = make_float4(acc0, acc1, acc2, acc3);
    *(float4*)(outp + (b * 69 + i) * 128 + d0) = ov;
  }
}

extern "C" void kernel_launch(void* const* d_in, const int* in_sizes, int n_in,
                              void* d_out, int out_size, void* d_ws, size_t ws_size,
                              hipStream_t stream) {
  (void)in_sizes; (void)n_in; (void)out_size;
  // Sb(bf16) 18,087,936 | alpha 16,384 | scA 19,501,056 | scB 19,501,056 = 57,106,432 B
  if (ws_size < 57106432u) return;  // early-return signature: absmax == 7.08e-2
  const float* in1 = (const float*)d_in[0];
  const float* in2 = (const float*)d_in[1];
  const float* se  = (const float*)d_in[2];
  const int* adjS  = (const int*)d_in[3];
  const int* adjND = (const int*)d_in[4];
  const float* mask = (const float*)d_in[5];
  const int* iidx  = (const int*)d_in[6];
  const float* Wl  = (const float*)d_in[8];
  const float* bl  = (const float*)d_in[9];
  const float* w1p = (const float*)d_in[10];
  const float* b1p = (const float*)d_in[11];
  const float* w2p = (const float*)d_in[12];
  const float* b2p = (const float*)d_in[13];
  const float* wSp = (const float*)d_in[14];
  const float* bSp = (const float*)d_in[15];
  const float* A1  = (const float*)d_in[16];
  const float* S1  = (const float*)d_in[17];
  const float* A2  = (const float*)d_in[18];
  const float* S2  = (const float*)d_in[19];
  ushort* Sb   = (ushort*)d_ws;
  float* alpha = (float*)((char*)d_ws + 18087936);
  float* scA   = (float*)((char*)d_ws + 18104320);
  float* scB   = (float*)((char*)d_ws + 37605376);
  float* outp  = (float*)d_out;

  k0_wproj<<<dim3(1), dim3(128), 0, stream>>>(Wl, bl, wSp, alpha);
  k1_mfma<<<dim3(1024), dim3(512), 0, stream>>>(se, Wl, bl, Sb);
  k2_alpha<<<dim3(1024), dim3(128), 0, stream>>>(in1, in2, se, mask, iidx,
                                                 w1p, b1p, w2p, b2p, bSp, alpha);
  // out1
  k3_scores<<<dim3(1024, 2), dim3(256), 0, stream>>>(in1, A1, scA, Sb, S1, scB, adjS);
  k4_entmax<<<dim3(4416), dim3(256), 0, stream>>>(alpha, 0, scA, scB);
  k5_out<<<dim3(1024), dim3(256), 0, stream>>>(in1, scA, outp);
  // out2
  k3_scores<<<dim3(1024, 2), dim3(256), 0, stream>>>(in2, A2, scA, Sb, S2, scB, adjND);
  k4_entmax<<<dim3(4416), dim3(256), 0, stream>>>(alpha, 1, scA, scB);
  k5_out<<<dim3(1024), dim3(256), 0, stream>>>(in2, scA, outp + SZ_S);
}